// Round 1
// baseline (9744.119 us; speedup 1.0000x reference)
//
#include <hip/hip_runtime.h>
#include <math.h>

#define FLAG_RELU 1
#define FLAG_BIAS 2
#define FLAG_ACC  4

static constexpr int BB   = 2;
static constexpr int N0   = 10000;
static constexpr int DIN  = 1024;
static constexpr int D    = 512;
static constexpr int NH   = 8;
static constexpr int DH   = 64;
static constexpr int MM   = 256;    // landmarks
static constexpr int SEQ  = 10240;  // padded n
static constexpr int PADR = 239;    // front zero-pad rows
static constexpr int NTOK = 10001;  // n0
static constexpr int LL   = 40;     // l = SEQ/MM
static constexpr float EPS_ = 1e-5f;

// ---------------------------------------------------------------- utilities
__device__ __forceinline__ void atomicMaxPosF(float* addr, float v) {
    atomicMax((unsigned int*)addr, __float_as_uint(v)); // valid for v >= 0
}

// ---------------------------------------------------------------- SGEMM (NN)
// C(MxN,ldc) = op( A(MxK,lda) @ B(KxN,ldb) ); K multiple of 16, N multiple of 64.
__global__ __launch_bounds__(256)
void sgemm_nn(const float* __restrict__ A, const float* __restrict__ Bm,
              float* __restrict__ C, const float* __restrict__ bias,
              int M, int N, int K, int lda, int ldb, int ldc,
              int flags, int qcols, float qscale)
{
    __shared__ float As[16][66];   // [k][m], padded to avoid write conflicts
    __shared__ float Bs[16][64];   // [k][n]
    int t  = threadIdx.x;
    int m0 = blockIdx.y * 64;
    int n0 = blockIdx.x * 64;
    int aRow = t >> 2, aCol = (t & 3) * 4;
    int bRow = t >> 4, bCol = (t & 15) * 4;
    int tm = t >> 4, tn = t & 15;
    float acc[4][4] = {};
    for (int k0 = 0; k0 < K; k0 += 16) {
        int gm = m0 + aRow;
        if (gm < M) {
            const float* ap = A + (size_t)gm * lda + k0 + aCol;
            As[aCol+0][aRow] = ap[0];
            As[aCol+1][aRow] = ap[1];
            As[aCol+2][aRow] = ap[2];
            As[aCol+3][aRow] = ap[3];
        } else {
            As[aCol+0][aRow] = 0.f; As[aCol+1][aRow] = 0.f;
            As[aCol+2][aRow] = 0.f; As[aCol+3][aRow] = 0.f;
        }
        float4 b4 = *(const float4*)(Bm + (size_t)(k0 + bRow) * ldb + n0 + bCol);
        *(float4*)&Bs[bRow][bCol] = b4;
        __syncthreads();
        #pragma unroll
        for (int kk = 0; kk < 16; kk++) {
            float av[4], bw[4];
            #pragma unroll
            for (int i = 0; i < 4; i++) av[i] = As[kk][tm*4+i];
            #pragma unroll
            for (int j = 0; j < 4; j++) bw[j] = Bs[kk][tn*4+j];
            #pragma unroll
            for (int i = 0; i < 4; i++)
                #pragma unroll
                for (int j = 0; j < 4; j++)
                    acc[i][j] = fmaf(av[i], bw[j], acc[i][j]);
        }
        __syncthreads();
    }
    #pragma unroll
    for (int i = 0; i < 4; i++) {
        int gm = m0 + tm*4 + i;
        if (gm >= M) continue;
        float* crow = C + (size_t)gm * ldc;
        #pragma unroll
        for (int j = 0; j < 4; j++) {
            int gn = n0 + tn*4 + j;
            float v = acc[i][j];
            if (gn < qcols) v *= qscale;
            if (flags & FLAG_BIAS) v += bias[gn];
            if (flags & FLAG_RELU) v = fmaxf(v, 0.0f);
            if (flags & FLAG_ACC)  v += crow[gn];
            crow[gn] = v;
        }
    }
}

// ------------------------------------------------- batched GEMM with dI+s*B
// slab g = slab0+blockIdx.z; b=g>>3,h=g&7.  A indexed by LOCAL z (zi*sAz).
// C[g] = osc * A @ (dg*I + bsc*B[g]).  M,N mult of 64, K mult of 16.
__global__ __launch_bounds__(256)
void bgemm(const float* __restrict__ Abase, long long sAz, int lda,
           const float* __restrict__ Bbase, long long sBb, long long sBh, int ldb,
           float* __restrict__ Cbase, long long sCb, long long sCh, int ldc,
           int M, int N, int K, float dg, float bsc, float osc, int slab0)
{
    int zi = blockIdx.z;
    int g  = slab0 + zi;
    int b  = g >> 3, h = g & 7;
    const float* A  = Abase + (size_t)zi * sAz;
    const float* Bm = Bbase + (size_t)b * sBb + (size_t)h * sBh;
    float*       C  = Cbase + (size_t)b * sCb + (size_t)h * sCh;
    __shared__ float As[16][66];
    __shared__ float Bs[16][64];
    int t  = threadIdx.x;
    int m0 = blockIdx.y * 64;
    int n0 = blockIdx.x * 64;
    int aRow = t >> 2, aCol = (t & 3) * 4;
    int bRow = t >> 4, bCol = (t & 15) * 4;
    int tm = t >> 4, tn = t & 15;
    float acc[4][4] = {};
    for (int k0 = 0; k0 < K; k0 += 16) {
        float4 a4 = *(const float4*)(A + (size_t)(m0 + aRow) * lda + k0 + aCol);
        As[aCol+0][aRow] = a4.x; As[aCol+1][aRow] = a4.y;
        As[aCol+2][aRow] = a4.z; As[aCol+3][aRow] = a4.w;
        int gk = k0 + bRow;
        float4 b4 = *(const float4*)(Bm + (size_t)gk * ldb + n0 + bCol);
        Bs[bRow][bCol+0] = bsc*b4.x + ((gk == n0+bCol+0) ? dg : 0.f);
        Bs[bRow][bCol+1] = bsc*b4.y + ((gk == n0+bCol+1) ? dg : 0.f);
        Bs[bRow][bCol+2] = bsc*b4.z + ((gk == n0+bCol+2) ? dg : 0.f);
        Bs[bRow][bCol+3] = bsc*b4.w + ((gk == n0+bCol+3) ? dg : 0.f);
        __syncthreads();
        #pragma unroll
        for (int kk = 0; kk < 16; kk++) {
            float av[4], bw[4];
            #pragma unroll
            for (int i = 0; i < 4; i++) av[i] = As[kk][tm*4+i];
            #pragma unroll
            for (int j = 0; j < 4; j++) bw[j] = Bs[kk][tn*4+j];
            #pragma unroll
            for (int i = 0; i < 4; i++)
                #pragma unroll
                for (int j = 0; j < 4; j++)
                    acc[i][j] = fmaf(av[i], bw[j], acc[i][j]);
        }
        __syncthreads();
    }
    #pragma unroll
    for (int i = 0; i < 4; i++) {
        float* crow = C + (size_t)(m0 + tm*4 + i) * ldc + n0;
        #pragma unroll
        for (int j = 0; j < 4; j++) crow[tn*4+j] = osc * acc[i][j];
    }
}

// ---------------------------------------------------------------- small ops
__global__ void fill_cls(const float* __restrict__ cls, float* __restrict__ H) {
    H[(size_t)blockIdx.x * NTOK * D + threadIdx.x] = cls[threadIdx.x];
}

// LayerNorm + front zero-pad into (B,SEQ,D)
__global__ __launch_bounds__(256)
void ln_pad(const float* __restrict__ H, const float* __restrict__ g,
            const float* __restrict__ bt, float* __restrict__ out)
{
    int blk = blockIdx.x;              // 0 .. BB*SEQ-1
    int b = blk / SEQ, i = blk % SEQ;
    int t = threadIdx.x;
    float* orow = out + (size_t)blk * D;
    if (i < PADR) { orow[t] = 0.f; orow[t+256] = 0.f; return; }
    const float* x = H + ((size_t)b * NTOK + (i - PADR)) * D;
    float v0 = x[t], v1 = x[t+256];
    __shared__ float red[256];
    red[t] = v0 + v1; __syncthreads();
    for (int o = 128; o > 0; o >>= 1) { if (t < o) red[t] += red[t+o]; __syncthreads(); }
    float mu = red[0] * (1.0f / D); __syncthreads();
    float d0 = v0 - mu, d1 = v1 - mu;
    red[t] = d0*d0 + d1*d1; __syncthreads();
    for (int o = 128; o > 0; o >>= 1) { if (t < o) red[t] += red[t+o]; __syncthreads(); }
    float rs = rsqrtf(red[0] * (1.0f / D) + EPS_);
    orow[t]     = d0 * rs * g[t]     + bt[t];
    orow[t+256] = d1 * rs * g[t+256] + bt[t+256];
}

// landmarks: q_l (B,NH,MM,DH) and k_l transposed (B,NH,DH,MM)
__global__ void landmarks(const float* __restrict__ qkv,
                          float* __restrict__ ql, float* __restrict__ klt)
{
    int blk = blockIdx.x;               // b*NH*MM + h*MM + m
    int m = blk & 255, h = (blk >> 8) & 7, b = blk >> 11;
    int d = threadIdx.x;                // 64
    const float* base = qkv + (size_t)b * SEQ * 1536 + (size_t)(m * LL) * 1536;
    float sq = 0.f, sk = 0.f;
    for (int tt = 0; tt < LL; tt++) {
        const float* r = base + (size_t)tt * 1536;
        sq += r[h*DH + d];
        sk += r[D + h*DH + d];
    }
    int slab = b * NH + h;
    ql [((size_t)slab * MM + m) * DH + d] = sq * (1.0f / LL);
    klt[((size_t)slab * DH + d) * MM + m] = sk * (1.0f / LL);
}

// a2 = softmax(q_l @ k_l^T) rows; one block per (slab,m)
__global__ __launch_bounds__(256)
void s2_softmax(const float* __restrict__ ql, const float* __restrict__ klt,
                float* __restrict__ a2)
{
    int blk = blockIdx.x;
    int m = blk & 255, slab = blk >> 8;
    int j = threadIdx.x;
    __shared__ float q[64];
    __shared__ float red[256];
    if (j < 64) q[j] = ql[((size_t)slab * MM + m) * DH + j];
    __syncthreads();
    const float* kt = klt + (size_t)slab * DH * MM;
    float s = 0.f;
    #pragma unroll 8
    for (int kk = 0; kk < 64; kk++) s = fmaf(q[kk], kt[kk*MM + j], s);
    red[j] = s; __syncthreads();
    for (int o = 128; o > 0; o >>= 1) { if (j < o) red[j] = fmaxf(red[j], red[j+o]); __syncthreads(); }
    float mx = red[0]; __syncthreads();
    float e = expf(s - mx);
    red[j] = e; __syncthreads();
    for (int o = 128; o > 0; o >>= 1) { if (j < o) red[j] += red[j+o]; __syncthreads(); }
    a2[((size_t)slab * MM + m) * MM + j] = e / red[0];
}

__global__ void zero_scr(float* s) { if (threadIdx.x < 2) s[threadIdx.x] = 0.f; }

// global max of |a2| row-sums and col-sums (reference's jnp.max over all axes)
__global__ __launch_bounds__(256)
void a2_alpha(const float* __restrict__ a2, float* __restrict__ scr)
{
    int slab = blockIdx.x, t = threadIdx.x;
    const float* A = a2 + (size_t)slab * MM * MM;
    float cs = 0.f, rs = 0.f;
    for (int r = 0; r < MM; r++) cs += fabsf(A[(size_t)r * MM + t]);   // col-sum (axis -2)
    for (int c = 0; c < MM; c++) rs += fabsf(A[(size_t)t * MM + c]);   // row-sum (axis -1)
    __shared__ float red[256];
    red[t] = rs; __syncthreads();
    for (int o = 128; o > 0; o >>= 1) { if (t < o) red[t] = fmaxf(red[t], red[t+o]); __syncthreads(); }
    float mrs = red[0]; __syncthreads();
    red[t] = cs; __syncthreads();
    for (int o = 128; o > 0; o >>= 1) { if (t < o) red[t] = fmaxf(red[t], red[t+o]); __syncthreads(); }
    float mcs = red[0];
    if (t == 0) { atomicMaxPosF(scr + 0, mrs); atomicMaxPosF(scr + 1, mcs); }
}

__global__ __launch_bounds__(256)
void z_init(const float* __restrict__ a2, const float* __restrict__ scr,
            float* __restrict__ z)
{
    size_t idx = (size_t)blockIdx.x * 256 + threadIdx.x;
    int slab = (int)(idx >> 16), r = (int)((idx >> 8) & 255), c = (int)(idx & 255);
    float inv = 1.0f / (scr[0] * scr[1]);
    z[idx] = a2[((size_t)slab << 16) + (size_t)c * MM + r] * inv;
}

// s3 scores: S3[zi] (MM x SEQ) = q_l[g] @ k[g]^T  (K=64 in one LDS tile)
__global__ __launch_bounds__(256)
void s3_scores(const float* __restrict__ ql, const float* __restrict__ qkv,
               float* __restrict__ s3, int slab0)
{
    int zi = blockIdx.z, g = slab0 + zi;
    int b = g >> 3, h = g & 7;
    int j0 = blockIdx.x * 64, m0 = blockIdx.y * 64;
    __shared__ float Qs[64][65];   // [k][m]
    __shared__ float Ks[64][65];   // [k][j]
    int t = threadIdx.x;
    int lr = t >> 4, lc = (t & 15) * 4;
    const float* Qb = ql + ((size_t)g * MM + m0) * DH;
    const float* Kb = qkv + (size_t)b * SEQ * 1536 + D + h * DH;
    for (int r = 0; r < 4; r++) {
        int row = lr + r * 16;
        float4 q4 = *(const float4*)(Qb + (size_t)row * DH + lc);
        Qs[lc+0][row] = q4.x; Qs[lc+1][row] = q4.y; Qs[lc+2][row] = q4.z; Qs[lc+3][row] = q4.w;
        float4 k4 = *(const float4*)(Kb + (size_t)(j0 + row) * 1536 + lc);
        Ks[lc+0][row] = k4.x; Ks[lc+1][row] = k4.y; Ks[lc+2][row] = k4.z; Ks[lc+3][row] = k4.w;
    }
    __syncthreads();
    int tm = t >> 4, tn = t & 15;
    float acc[4][4] = {};
    #pragma unroll 4
    for (int kk = 0; kk < 64; kk++) {
        float av[4], bv[4];
        #pragma unroll
        for (int i = 0; i < 4; i++) av[i] = Qs[kk][tm*4+i];
        #pragma unroll
        for (int j = 0; j < 4; j++) bv[j] = Ks[kk][tn*4+j];
        #pragma unroll
        for (int i = 0; i < 4; i++)
            #pragma unroll
            for (int j = 0; j < 4; j++)
                acc[i][j] = fmaf(av[i], bv[j], acc[i][j]);
    }
    float* Cb = s3 + (size_t)zi * MM * SEQ + (size_t)m0 * SEQ + j0;
    #pragma unroll
    for (int i = 0; i < 4; i++) {
        float4 o4 = make_float4(acc[i][0], acc[i][1], acc[i][2], acc[i][3]);
        *(float4*)(Cb + (size_t)(tm*4+i) * SEQ + tn*4) = o4;
    }
}

// in-place row softmax over SEQ
__global__ __launch_bounds__(256)
void s3_softmax(float* __restrict__ s3)
{
    float* row = s3 + (size_t)blockIdx.x * SEQ;
    int t = threadIdx.x;
    __shared__ float red[256];
    float mx = -3.4e38f;
    for (int j = t; j < SEQ; j += 256) mx = fmaxf(mx, row[j]);
    red[t] = mx; __syncthreads();
    for (int o = 128; o > 0; o >>= 1) { if (t < o) red[t] = fmaxf(red[t], red[t+o]); __syncthreads(); }
    mx = red[0]; __syncthreads();
    float sum = 0.f;
    for (int j = t; j < SEQ; j += 256) { float e = expf(row[j] - mx); row[j] = e; sum += e; }
    red[t] = sum; __syncthreads();
    for (int o = 128; o > 0; o >>= 1) { if (t < o) red[t] += red[t+o]; __syncthreads(); }
    float inv = 1.0f / red[0];
    for (int j = t; j < SEQ; j += 256) row[j] *= inv;
}

// fused a1: attn[b,i,h*64+d] = softmax_j(q_i . k_l_j) @ W ; 4 rows per block
__global__ __launch_bounds__(256)
void a1_out(const float* __restrict__ qkv, const float* __restrict__ klt,
            const float* __restrict__ Wm, float* __restrict__ attn)
{
    int blk = blockIdx.x;
    int slab = blk / (SEQ/4);
    int i0   = (blk % (SEQ/4)) * 4;
    int b = slab >> 3, h = slab & 7;
    int t = threadIdx.x;
    __shared__ float q[4][64];
    __shared__ float p[4][256];
    __shared__ float red[256];
    __shared__ float part[4][4][64];
    { int r = t >> 6, d = t & 63;
      q[r][d] = qkv[((size_t)b*SEQ + i0 + r) * 1536 + h*DH + d]; }
    __syncthreads();
    const float* kt = klt + (size_t)slab * DH * MM;
    float s[4] = {0.f,0.f,0.f,0.f};
    #pragma unroll 8
    for (int kk = 0; kk < 64; kk++) {
        float kv = kt[kk*MM + t];
        s[0] = fmaf(q[0][kk], kv, s[0]); s[1] = fmaf(q[1][kk], kv, s[1]);
        s[2] = fmaf(q[2][kk], kv, s[2]); s[3] = fmaf(q[3][kk], kv, s[3]);
    }
    for (int r = 0; r < 4; r++) {
        red[t] = s[r]; __syncthreads();
        for (int o = 128; o > 0; o >>= 1) { if (t < o) red[t] = fmaxf(red[t], red[t+o]); __syncthreads(); }
        float mx = red[0]; __syncthreads();
        float e = expf(s[r] - mx);
        red[t] = e; __syncthreads();
        for (int o = 128; o > 0; o >>= 1) { if (t < o) red[t] += red[t+o]; __syncthreads(); }
        p[r][t] = e / red[0];
        __syncthreads();
    }
    int d = t & 63, jg = t >> 6;
    const float* Wp = Wm + (size_t)slab * MM * DH;
    float a[4] = {0.f,0.f,0.f,0.f};
    #pragma unroll 4
    for (int jj = 0; jj < 64; jj++) {
        int j = jg*64 + jj;
        float w = Wp[(size_t)j * DH + d];
        a[0] = fmaf(p[0][j], w, a[0]); a[1] = fmaf(p[1][j], w, a[1]);
        a[2] = fmaf(p[2][j], w, a[2]); a[3] = fmaf(p[3][j], w, a[3]);
    }
    for (int r = 0; r < 4; r++) part[r][jg][d] = a[r];
    __syncthreads();
    { int r = t >> 6, d2 = t & 63;
      float o = part[r][0][d2] + part[r][1][d2] + part[r][2][d2] + part[r][3][d2];
      attn[((size_t)b*SEQ + i0 + r) * D + h*DH + d2] = o; }
}

// depthwise 33x1 conv over sequence of v, added into attn
__global__ __launch_bounds__(512)
void res_add(const float* __restrict__ qkv, const float* __restrict__ rw,
             float* __restrict__ attn)
{
    int blk = blockIdx.x;             // b*SEQ + i
    int b = blk / SEQ, i = blk % SEQ;
    int c = threadIdx.x, h = c >> 6;
    __shared__ float w[NH*33];
    if (c < NH*33) w[c] = rw[c];
    __syncthreads();
    size_t oidx = ((size_t)b*SEQ + i) * D + c;
    float acc = attn[oidx];
    const float* vbase = qkv + (size_t)b * SEQ * 1536 + 2*D + c;
    #pragma unroll
    for (int ky = 0; ky < 33; ky++) {
        int j = i + ky - 16;
        if ((unsigned)j < (unsigned)SEQ)
            acc = fmaf(vbase[(size_t)j * 1536], w[h*33 + ky], acc);
    }
    attn[oidx] = acc;
}

// PPEG: y = x + dw7(x)+b7 + dw5(x)+b5 + dw3(x)+b3 over (100,100) image
__global__ __launch_bounds__(512)
void ppeg_conv(const float* __restrict__ H,
               const float* __restrict__ w7, const float* __restrict__ b7,
               const float* __restrict__ w5, const float* __restrict__ b5,
               const float* __restrict__ w3, const float* __restrict__ b3,
               float* __restrict__ outp)
{
    int blk = blockIdx.x;
    int b = blk / (100*100), pos = blk % (100*100);
    int y = pos / 100, x = pos % 100;
    int c = threadIdx.x;
    const float* Hb = H + ((size_t)b * NTOK + 1) * D + c;
    float acc = Hb[(size_t)pos * D] + b7[c] + b5[c] + b3[c];
    const float* wc7 = w7 + (size_t)c * 49;
    const float* wc5 = w5 + (size_t)c * 25;
    const float* wc3 = w3 + (size_t)c * 9;
    #pragma unroll
    for (int ky = 0; ky < 7; ky++) {
        int yy = y + ky - 3;
        if ((unsigned)yy >= 100u) continue;
        #pragma unroll
        for (int kx = 0; kx < 7; kx++) {
            int xx = x + kx - 3;
            if ((unsigned)xx >= 100u) continue;
            acc = fmaf(Hb[(size_t)(yy*100+xx) * D], wc7[ky*7+kx], acc);
        }
    }
    #pragma unroll
    for (int ky = 0; ky < 5; ky++) {
        int yy = y + ky - 2;
        if ((unsigned)yy >= 100u) continue;
        #pragma unroll
        for (int kx = 0; kx < 5; kx++) {
            int xx = x + kx - 2;
            if ((unsigned)xx >= 100u) continue;
            acc = fmaf(Hb[(size_t)(yy*100+xx) * D], wc5[ky*5+kx], acc);
        }
    }
    #pragma unroll
    for (int ky = 0; ky < 3; ky++) {
        int yy = y + ky - 1;
        if ((unsigned)yy >= 100u) continue;
        #pragma unroll
        for (int kx = 0; kx < 3; kx++) {
            int xx = x + kx - 1;
            if ((unsigned)xx >= 100u) continue;
            acc = fmaf(Hb[(size_t)(yy*100+xx) * D], wc3[ky*3+kx], acc);
        }
    }
    outp[(size_t)blk * D + c] = acc;
}

__global__ __launch_bounds__(512)
void ppeg_copy(const float* __restrict__ outp, float* __restrict__ H)
{
    int blk = blockIdx.x;
    int b = blk / (100*100), pos = blk % (100*100);
    H[((size_t)b * NTOK + 1 + pos) * D + threadIdx.x] = outp[(size_t)blk * D + threadIdx.x];
}

// final: LN(row0) @ w_fc2 + b ; softmax ; argmax -> 10 floats
__global__ __launch_bounds__(512)
void final_head(const float* __restrict__ H, const float* __restrict__ g,
                const float* __restrict__ bt, const float* __restrict__ w2,
                const float* __restrict__ b2, float* __restrict__ out)
{
    int b = blockIdx.x, t = threadIdx.x;
    __shared__ float red[512];
    float v = H[(size_t)b * NTOK * D + t];
    red[t] = v; __syncthreads();
    for (int o = 256; o > 0; o >>= 1) { if (t < o) red[t] += red[t+o]; __syncthreads(); }
    float mu = red[0] * (1.0f / D); __syncthreads();
    float dv = v - mu;
    red[t] = dv*dv; __syncthreads();
    for (int o = 256; o > 0; o >>= 1) { if (t < o) red[t] += red[t+o]; __syncthreads(); }
    float rstd = rsqrtf(red[0] * (1.0f / D) + EPS_); __syncthreads();
    float xn = dv * rstd * g[t] + bt[t];
    red[t] = xn * w2[2*t]; __syncthreads();
    for (int o = 256; o > 0; o >>= 1) { if (t < o) red[t] += red[t+o]; __syncthreads(); }
    float l0 = red[0] + b2[0]; __syncthreads();
    red[t] = xn * w2[2*t+1]; __syncthreads();
    for (int o = 256; o > 0; o >>= 1) { if (t < o) red[t] += red[t+o]; __syncthreads(); }
    float l1 = red[0] + b2[1];
    if (t == 0) {
        out[b*2+0] = l0; out[b*2+1] = l1;
        float mx = fmaxf(l0, l1);
        float e0 = expf(l0 - mx), e1 = expf(l1 - mx);
        float ssum = e0 + e1;
        out[4 + b*2 + 0] = e0 / ssum;
        out[4 + b*2 + 1] = e1 / ssum;
        out[8 + b] = (l1 > l0) ? 1.0f : 0.0f;
    }
}

// ---------------------------------------------------------------------------
extern "C" void kernel_launch(void* const* d_in, const int* in_sizes, int n_in,
                              void* d_out, int out_size, void* d_ws, size_t ws_size,
                              hipStream_t stream)
{
    const float* x      = (const float*)d_in[0];
    const float* w_fc1  = (const float*)d_in[1];
    const float* b_fc1  = (const float*)d_in[2];
    const float* cls    = (const float*)d_in[3];
    const float* ln1_g  = (const float*)d_in[4];
    const float* ln1_b  = (const float*)d_in[5];
    const float* qkv1_w = (const float*)d_in[6];
    const float* out1_w = (const float*)d_in[7];
    const float* out1_b = (const float*)d_in[8];
    const float* res1_w = (const float*)d_in[9];
    const float* ln2_g  = (const float*)d_in[10];
    const float* ln2_b  = (const float*)d_in[11];
    const float* qkv2_w = (const float*)d_in[12];
    const float* out2_w = (const float*)d_in[13];
    const float* out2_b = (const float*)d_in[14];
    const float* res2_w = (const float*)d_in[15];
    const float* pw7 = (const float*)d_in[16];
    const float* pb7 = (const float*)d_in[17];
    const float* pw5 = (const float*)d_in[18];
    const float* pb5 = (const float*)d_in[19];
    const float* pw3 = (const float*)d_in[20];
    const float* pb3 = (const float*)d_in[21];
    const float* lnf_g = (const float*)d_in[22];
    const float* lnf_b = (const float*)d_in[23];
    const float* w_fc2 = (const float*)d_in[24];
    const float* b_fc2 = (const float*)d_in[25];

    // workspace carve-up (~322 MB total, fp32)
    float* ws = (float*)d_ws;
    size_t off = 0;
    auto alloc = [&](size_t n) { float* p = ws + off; off += (n + 63) & ~(size_t)63; return p; };
    float* H    = alloc((size_t)BB * NTOK * D);      // 40.9 MB
    float* LN   = alloc((size_t)BB * SEQ * D);       // 41.9 MB (aliased as ATTN / ppeg tmp)
    float* QKV  = alloc((size_t)BB * SEQ * 3 * D);   // 125.8 MB
    float* QL   = alloc((size_t)BB * NH * MM * DH);
    float* KLT  = alloc((size_t)BB * NH * DH * MM);
    float* A2   = alloc((size_t)BB * NH * MM * MM);
    float* ZA   = alloc((size_t)BB * NH * MM * MM);
    float* ZB   = alloc((size_t)BB * NH * MM * MM);
    float* XZ   = alloc((size_t)BB * NH * MM * MM);
    float* T1   = alloc((size_t)BB * NH * MM * MM);
    float* T2   = alloc((size_t)BB * NH * MM * MM);
    float* A3V  = alloc((size_t)BB * NH * MM * DH);
    float* WB   = alloc((size_t)BB * NH * MM * DH);
    float* S3   = alloc((size_t)8 * MM * SEQ);       // 83.9 MB (half the slabs at a time)
    float* SCR  = alloc(64);
    float* ATTN = LN;                                // reuse: LN dead after qkv GEMM
    (void)ws_size; (void)in_sizes; (void)n_in; (void)out_size;

    // 1) h = relu(x @ w_fc1 + b_fc1) into H rows 1..N0 ; cls row 0
    for (int b = 0; b < BB; b++) {
        dim3 g(D/64, (N0 + 63)/64);
        sgemm_nn<<<g, 256, 0, stream>>>(x + (size_t)b*N0*DIN, w_fc1,
            H + ((size_t)b*NTOK + 1)*D, b_fc1,
            N0, D, DIN, DIN, D, D, FLAG_BIAS|FLAG_RELU, 0, 1.f);
    }
    fill_cls<<<BB, D, 0, stream>>>(cls, H);

    auto attention = [&](const float* lg, const float* lb, const float* qw,
                         const float* ow, const float* ob, const float* rw)
    {
        ln_pad<<<BB*SEQ, 256, 0, stream>>>(H, lg, lb, LN);
        { dim3 g((3*D)/64, (BB*SEQ)/64);
          sgemm_nn<<<g, 256, 0, stream>>>(LN, qw, QKV, nullptr,
              BB*SEQ, 3*D, D, D, 3*D, 3*D, 0, D, 0.125f); }   // scale q block by DH^-0.5
        landmarks<<<BB*NH*MM, 64, 0, stream>>>(QKV, QL, KLT);
        s2_softmax<<<BB*NH*MM, 256, 0, stream>>>(QL, KLT, A2);
        zero_scr<<<1, 64, 0, stream>>>(SCR);
        a2_alpha<<<BB*NH, 256, 0, stream>>>(A2, SCR);
        z_init<<<BB*NH*MM*MM/256, 256, 0, stream>>>(A2, SCR, ZA);
        float* z = ZA; float* zn = ZB;
        for (int it = 0; it < 6; it++) {
            dim3 g(4, 4, 16);
            bgemm<<<g,256,0,stream>>>(A2, 65536LL, MM,  z, 8LL*65536, 65536LL, MM,
                                      XZ, 8LL*65536, 65536LL, MM, MM, MM, MM, 0.f, 1.f, 1.f, 0);
            bgemm<<<g,256,0,stream>>>(XZ, 65536LL, MM,  XZ, 8LL*65536, 65536LL, MM,
                                      T1, 8LL*65536, 65536LL, MM, MM, MM, MM, 7.f, -1.f, 1.f, 0);
            bgemm<<<g,256,0,stream>>>(XZ, 65536LL, MM,  T1, 8LL*65536, 65536LL, MM,
                                      T2, 8LL*65536, 65536LL, MM, MM, MM, MM, 15.f, -1.f, 1.f, 0);
            bgemm<<<g,256,0,stream>>>(z, 65536LL, MM,  T2, 8LL*65536, 65536LL, MM,
                                      zn, 8LL*65536, 65536LL, MM, MM, MM, MM, 13.f, -1.f, 0.25f, 0);
            float* tsw = z; z = zn; zn = tsw;
        }
        for (int grp = 0; grp < 2; grp++) {
            int slab0 = grp * 8;
            s3_scores<<<dim3(SEQ/64, MM/64, 8), 256, 0, stream>>>(QL, QKV, S3, slab0);
            s3_softmax<<<8*MM, 256, 0, stream>>>(S3);
            bgemm<<<dim3(1, MM/64, 8), 256, 0, stream>>>(
                S3, (long long)MM*SEQ, SEQ,
                QKV + 2*D, (long long)SEQ*1536, 64LL, 1536,
                A3V, 8LL*MM*DH, (long long)MM*DH, DH,
                MM, DH, SEQ, 0.f, 1.f, 1.f, slab0);
        }
        bgemm<<<dim3(1, MM/64, 16), 256, 0, stream>>>(
            z, 65536LL, MM,
            A3V, 8LL*MM*DH, (long long)MM*DH, DH,
            WB, 8LL*MM*DH, (long long)MM*DH, DH,
            MM, DH, MM, 0.f, 1.f, 1.f, 0);
        a1_out<<<BB*NH*(SEQ/4), 256, 0, stream>>>(QKV, KLT, WB, ATTN);
        res_add<<<BB*SEQ, 512, 0, stream>>>(QKV, rw, ATTN);
        for (int b = 0; b < BB; b++) {
            dim3 g(D/64, (NTOK + 63)/64);
            sgemm_nn<<<g, 256, 0, stream>>>(ATTN + ((size_t)b*SEQ + PADR)*D, ow,
                H + (size_t)b*NTOK*D, ob,
                NTOK, D, D, D, D, D, FLAG_BIAS|FLAG_ACC, 0, 1.f);
        }
    };

    // 2) attention block 1
    attention(ln1_g, ln1_b, qkv1_w, out1_w, out1_b, res1_w);

    // 3) PPEG (LN buffer as temp; feat replaced, cls untouched)
    ppeg_conv<<<BB*100*100, 512, 0, stream>>>(H, pw7, pb7, pw5, pb5, pw3, pb3, LN);
    ppeg_copy<<<BB*100*100, 512, 0, stream>>>(LN, H);

    // 4) attention block 2
    attention(ln2_g, ln2_b, qkv2_w, out2_w, out2_b, res2_w);

    // 5) head
    final_head<<<BB, 512, 0, stream>>>(H, lnf_g, lnf_b, w_fc2, b_fc2, (float*)d_out);
}

// Round 2
// 4156.346 us; speedup vs baseline: 2.3444x; 2.3444x over previous
//
#include <hip/hip_runtime.h>
#include <math.h>

#define FLAG_RELU 1
#define FLAG_BIAS 2
#define FLAG_ACC  4

static constexpr int BB   = 2;
static constexpr int N0   = 10000;
static constexpr int DIN  = 1024;
static constexpr int D    = 512;
static constexpr int NH   = 8;
static constexpr int DH   = 64;
static constexpr int MM   = 256;    // landmarks
static constexpr int SEQ  = 10240;  // padded n
static constexpr int PADR = 239;    // front zero-pad rows
static constexpr int NTOK = 10001;  // n0
static constexpr int LL   = 40;     // l = SEQ/MM
static constexpr float EPS_ = 1e-5f;

__device__ __forceinline__ void atomicMaxPosF(float* addr, float v) {
    atomicMax((unsigned int*)addr, __float_as_uint(v)); // valid for v >= 0
}

// ------------------------------------------------------------- SGEMM 128x128
// C(MxN) = op(A(MxK) @ B(KxN)); N mult of 128, K mult of 8; M guarded.
__global__ __launch_bounds__(256)
void sgemm128(const float* __restrict__ A, const float* __restrict__ Bm,
              float* __restrict__ C, const float* __restrict__ bias,
              int M, int N, int K, int lda, int ldb, int ldc,
              int flags, int qcols, float qscale)
{
    __shared__ float As[8][132];   // stride 132: 16B-aligned rows, 2-way banks
    __shared__ float Bs[8][132];
    int t = threadIdx.x;
    int m0 = blockIdx.y * 128, n0 = blockIdx.x * 128;
    int arow = t >> 1, acg = (t & 1) * 4;
    int brow = t >> 5, bcol = (t & 31) * 4;
    int tm = t >> 4, tn = t & 15;
    float acc[2][2][4][4] = {};
    for (int k0 = 0; k0 < K; k0 += 8) {
        int gm = m0 + arow;
        float4 a4 = make_float4(0.f, 0.f, 0.f, 0.f);
        if (gm < M) a4 = *(const float4*)(A + (size_t)gm * lda + k0 + acg);
        As[acg+0][arow] = a4.x; As[acg+1][arow] = a4.y;
        As[acg+2][arow] = a4.z; As[acg+3][arow] = a4.w;
        float4 b4 = *(const float4*)(Bm + (size_t)(k0 + brow) * ldb + n0 + bcol);
        *(float4*)&Bs[brow][bcol] = b4;
        __syncthreads();
        #pragma unroll
        for (int kk = 0; kk < 8; kk++) {
            float4 a0 = *(const float4*)&As[kk][tm*4];
            float4 a1 = *(const float4*)&As[kk][tm*4 + 64];
            float4 b0 = *(const float4*)&Bs[kk][tn*4];
            float4 b1 = *(const float4*)&Bs[kk][tn*4 + 64];
            float av[2][4] = {{a0.x,a0.y,a0.z,a0.w},{a1.x,a1.y,a1.z,a1.w}};
            float bv[2][4] = {{b0.x,b0.y,b0.z,b0.w},{b1.x,b1.y,b1.z,b1.w}};
            #pragma unroll
            for (int im = 0; im < 2; im++)
                #pragma unroll
                for (int i = 0; i < 4; i++)
                    #pragma unroll
                    for (int jn = 0; jn < 2; jn++)
                        #pragma unroll
                        for (int j = 0; j < 4; j++)
                            acc[im][jn][i][j] = fmaf(av[im][i], bv[jn][j], acc[im][jn][i][j]);
        }
        __syncthreads();
    }
    #pragma unroll
    for (int im = 0; im < 2; im++)
        #pragma unroll
        for (int i = 0; i < 4; i++) {
            int gm = m0 + im*64 + tm*4 + i;
            if (gm >= M) continue;
            #pragma unroll
            for (int jn = 0; jn < 2; jn++) {
                int gn = n0 + jn*64 + tn*4;
                float v[4];
                #pragma unroll
                for (int j = 0; j < 4; j++) {
                    float u = acc[im][jn][i][j];
                    if (gn + j < qcols) u *= qscale;
                    if (flags & FLAG_BIAS) u += bias[gn + j];
                    if (flags & FLAG_RELU) u = fmaxf(u, 0.f);
                    v[j] = u;
                }
                float* cp = C + (size_t)gm * ldc + gn;
                if (flags & FLAG_ACC) {
                    float4 old = *(const float4*)cp;
                    v[0] += old.x; v[1] += old.y; v[2] += old.z; v[3] += old.w;
                }
                *(float4*)cp = make_float4(v[0], v[1], v[2], v[3]);
            }
        }
}

// ------------------------------------------------- batched GEMM with dI+s*B
// slab g = slab0+z; b=g>>3,h=g&7.  C[g] = osc * A @ (dg*I + bsc*B[g]).
// M,N mult of 64, K mult of 16.
__global__ __launch_bounds__(256)
void bgemm(const float* __restrict__ Abase, long long sAz, int lda,
           const float* __restrict__ Bbase, long long sBb, long long sBh, int ldb,
           float* __restrict__ Cbase, long long sCb, long long sCh, int ldc,
           int M, int N, int K, float dg, float bsc, float osc, int slab0)
{
    int zi = blockIdx.z;
    int g  = slab0 + zi;
    int b  = g >> 3, h = g & 7;
    const float* A  = Abase + (size_t)zi * sAz;
    const float* Bm = Bbase + (size_t)b * sBb + (size_t)h * sBh;
    float*       C  = Cbase + (size_t)b * sCb + (size_t)h * sCh;
    __shared__ float As[16][68];
    __shared__ float Bs[16][68];
    int t  = threadIdx.x;
    int m0 = blockIdx.y * 64, n0 = blockIdx.x * 64;
    int aRow = t >> 2, aCol = (t & 3) * 4;
    int bRow = t >> 4, bCol = (t & 15) * 4;
    int tm = t >> 4, tn = t & 15;
    float acc[4][4] = {};
    for (int k0 = 0; k0 < K; k0 += 16) {
        float4 a4 = *(const float4*)(A + (size_t)(m0 + aRow) * lda + k0 + aCol);
        As[aCol+0][aRow] = a4.x; As[aCol+1][aRow] = a4.y;
        As[aCol+2][aRow] = a4.z; As[aCol+3][aRow] = a4.w;
        int gk = k0 + bRow;
        float4 b4 = *(const float4*)(Bm + (size_t)gk * ldb + n0 + bCol);
        float4 bb;
        bb.x = bsc*b4.x + ((gk == n0+bCol+0) ? dg : 0.f);
        bb.y = bsc*b4.y + ((gk == n0+bCol+1) ? dg : 0.f);
        bb.z = bsc*b4.z + ((gk == n0+bCol+2) ? dg : 0.f);
        bb.w = bsc*b4.w + ((gk == n0+bCol+3) ? dg : 0.f);
        *(float4*)&Bs[bRow][bCol] = bb;
        __syncthreads();
        #pragma unroll
        for (int kk = 0; kk < 16; kk++) {
            float4 a = *(const float4*)&As[kk][tm*4];
            float4 bv = *(const float4*)&Bs[kk][tn*4];
            float avv[4] = {a.x,a.y,a.z,a.w};
            float bvv[4] = {bv.x,bv.y,bv.z,bv.w};
            #pragma unroll
            for (int i = 0; i < 4; i++)
                #pragma unroll
                for (int j = 0; j < 4; j++)
                    acc[i][j] = fmaf(avv[i], bvv[j], acc[i][j]);
        }
        __syncthreads();
    }
    #pragma unroll
    for (int i = 0; i < 4; i++) {
        float* cp = C + (size_t)(m0 + tm*4 + i) * ldc + n0 + tn*4;
        *(float4*)cp = make_float4(osc*acc[i][0], osc*acc[i][1], osc*acc[i][2], osc*acc[i][3]);
    }
}

// --------------------------------------------- a3@v with split-K + atomicAdd
// grid (1, MM/64, 8*16); zi = z>>4, chunk = z&15.  A3V must be pre-zeroed.
__global__ __launch_bounds__(256)
void a3v_sk(const float* __restrict__ S3, const float* __restrict__ qkv,
            float* __restrict__ A3V, int slab0)
{
    int zi = blockIdx.z >> 4, chunk = blockIdx.z & 15;
    int g = slab0 + zi, b = g >> 3, h = g & 7;
    const float* A  = S3 + (size_t)zi * MM * SEQ;
    const float* Bm = qkv + (size_t)b * SEQ * 1536 + 2*D + h*DH;
    float* C = A3V + (size_t)g * MM * DH;
    int m0 = blockIdx.y * 64;
    int kb = chunk * (SEQ/16), ke = kb + (SEQ/16);
    __shared__ float As[16][68];
    __shared__ float Bs[16][68];
    int t = threadIdx.x;
    int aRow = t >> 2, aCol = (t & 3) * 4;
    int bRow = t >> 4, bCol = (t & 15) * 4;
    int tm = t >> 4, tn = t & 15;
    float acc[4][4] = {};
    for (int k0 = kb; k0 < ke; k0 += 16) {
        float4 a4 = *(const float4*)(A + (size_t)(m0 + aRow) * SEQ + k0 + aCol);
        As[aCol+0][aRow] = a4.x; As[aCol+1][aRow] = a4.y;
        As[aCol+2][aRow] = a4.z; As[aCol+3][aRow] = a4.w;
        float4 b4 = *(const float4*)(Bm + (size_t)(k0 + bRow) * 1536 + bCol);
        *(float4*)&Bs[bRow][bCol] = b4;
        __syncthreads();
        #pragma unroll
        for (int kk = 0; kk < 16; kk++) {
            float4 a = *(const float4*)&As[kk][tm*4];
            float4 bv = *(const float4*)&Bs[kk][tn*4];
            float avv[4] = {a.x,a.y,a.z,a.w};
            float bvv[4] = {bv.x,bv.y,bv.z,bv.w};
            #pragma unroll
            for (int i = 0; i < 4; i++)
                #pragma unroll
                for (int j = 0; j < 4; j++)
                    acc[i][j] = fmaf(avv[i], bvv[j], acc[i][j]);
        }
        __syncthreads();
    }
    #pragma unroll
    for (int i = 0; i < 4; i++)
        #pragma unroll
        for (int j = 0; j < 4; j++)
            atomicAdd(&C[(size_t)(m0 + tm*4 + i) * DH + tn*4 + j], acc[i][j]);
}

// ---------------------------------------------------------------- small ops
__global__ void fill_cls(const float* __restrict__ cls, float* __restrict__ H) {
    H[(size_t)blockIdx.x * NTOK * D + threadIdx.x] = cls[threadIdx.x];
}

// LayerNorm + front zero-pad into (B,SEQ,D) — shuffle reductions
__global__ __launch_bounds__(256)
void ln_pad(const float* __restrict__ H, const float* __restrict__ g,
            const float* __restrict__ bt, float* __restrict__ out)
{
    int blk = blockIdx.x;
    int b = blk / SEQ, i = blk % SEQ;
    int t = threadIdx.x;
    float* orow = out + (size_t)blk * D;
    if (i < PADR) { orow[t] = 0.f; orow[t+256] = 0.f; return; }
    const float* x = H + ((size_t)b * NTOK + (i - PADR)) * D;
    float v0 = x[t], v1 = x[t+256];
    __shared__ float w1[4], w2[4];
    float s = v0 + v1;
    for (int o = 32; o > 0; o >>= 1) s += __shfl_xor(s, o);
    if ((t & 63) == 0) w1[t >> 6] = s;
    __syncthreads();
    float mu = (w1[0]+w1[1]+w1[2]+w1[3]) * (1.0f / D);
    float d0 = v0 - mu, d1 = v1 - mu;
    float q = d0*d0 + d1*d1;
    for (int o = 32; o > 0; o >>= 1) q += __shfl_xor(q, o);
    if ((t & 63) == 0) w2[t >> 6] = q;
    __syncthreads();
    float rs = rsqrtf((w2[0]+w2[1]+w2[2]+w2[3]) * (1.0f / D) + EPS_);
    orow[t]     = d0 * rs * g[t]     + bt[t];
    orow[t+256] = d1 * rs * g[t+256] + bt[t+256];
}

// landmarks: block per (b,m), 512 threads (one channel each), 4-way ILP
__global__ __launch_bounds__(512)
void landmarks(const float* __restrict__ qkv,
               float* __restrict__ ql, float* __restrict__ klt)
{
    int blk = blockIdx.x;
    int b = blk >> 8, m = blk & 255;
    int c = threadIdx.x;
    const float* base = qkv + ((size_t)b * SEQ + (size_t)m * LL) * 1536;
    float sq0=0,sq1=0,sq2=0,sq3=0, sk0=0,sk1=0,sk2=0,sk3=0;
    for (int tt = 0; tt < LL; tt += 4) {
        const float* r = base + (size_t)tt * 1536;
        sq0 += r[c];            sk0 += r[512 + c];
        sq1 += r[1536 + c];     sk1 += r[1536 + 512 + c];
        sq2 += r[3072 + c];     sk2 += r[3072 + 512 + c];
        sq3 += r[4608 + c];     sk3 += r[4608 + 512 + c];
    }
    float sq = (sq0+sq1+sq2+sq3) * (1.0f / LL);
    float sk = (sk0+sk1+sk2+sk3) * (1.0f / LL);
    int h = c >> 6, d = c & 63;
    int slab = b * NH + h;
    ql [((size_t)slab * MM + m) * DH + d] = sq;
    klt[((size_t)slab * DH + d) * MM + m] = sk;
}

// a2 = softmax(q_l @ k_l^T) rows
__global__ __launch_bounds__(256)
void s2_softmax(const float* __restrict__ ql, const float* __restrict__ klt,
                float* __restrict__ a2)
{
    int blk = blockIdx.x;
    int m = blk & 255, slab = blk >> 8;
    int j = threadIdx.x;
    __shared__ float q[64];
    __shared__ float red[256];
    if (j < 64) q[j] = ql[((size_t)slab * MM + m) * DH + j];
    __syncthreads();
    const float* kt = klt + (size_t)slab * DH * MM;
    float s = 0.f;
    #pragma unroll 8
    for (int kk = 0; kk < 64; kk++) s = fmaf(q[kk], kt[kk*MM + j], s);
    red[j] = s; __syncthreads();
    for (int o = 128; o > 0; o >>= 1) { if (j < o) red[j] = fmaxf(red[j], red[j+o]); __syncthreads(); }
    float mx = red[0]; __syncthreads();
    float e = expf(s - mx);
    red[j] = e; __syncthreads();
    for (int o = 128; o > 0; o >>= 1) { if (j < o) red[j] += red[j+o]; __syncthreads(); }
    a2[((size_t)slab * MM + m) * MM + j] = e / red[0];
}

__global__ void zero_scr(float* s) { if (threadIdx.x < 2) s[threadIdx.x] = 0.f; }

__global__ __launch_bounds__(256)
void a2_alpha(const float* __restrict__ a2, float* __restrict__ scr)
{
    int slab = blockIdx.x, t = threadIdx.x;
    const float* A = a2 + (size_t)slab * MM * MM;
    float cs = 0.f, rs = 0.f;
    for (int r = 0; r < MM; r++) cs += fabsf(A[(size_t)r * MM + t]);
    for (int c = 0; c < MM; c++) rs += fabsf(A[(size_t)t * MM + c]);
    __shared__ float red[256];
    red[t] = rs; __syncthreads();
    for (int o = 128; o > 0; o >>= 1) { if (t < o) red[t] = fmaxf(red[t], red[t+o]); __syncthreads(); }
    float mrs = red[0]; __syncthreads();
    red[t] = cs; __syncthreads();
    for (int o = 128; o > 0; o >>= 1) { if (t < o) red[t] = fmaxf(red[t], red[t+o]); __syncthreads(); }
    float mcs = red[0];
    if (t == 0) { atomicMaxPosF(scr + 0, mrs); atomicMaxPosF(scr + 1, mcs); }
}

__global__ __launch_bounds__(256)
void z_init(const float* __restrict__ a2, const float* __restrict__ scr,
            float* __restrict__ z)
{
    size_t idx = (size_t)blockIdx.x * 256 + threadIdx.x;
    int slab = (int)(idx >> 16), r = (int)((idx >> 8) & 255), c = (int)(idx & 255);
    float inv = 1.0f / (scr[0] * scr[1]);
    z[idx] = a2[((size_t)slab << 16) + (size_t)c * MM + r] * inv;
}

// s3 scores: S3[zi] (MM x SEQ) = q_l[g] @ k[g]^T (K=64 single tile)
__global__ __launch_bounds__(256)
void s3_scores(const float* __restrict__ ql, const float* __restrict__ qkv,
               float* __restrict__ s3, int slab0)
{
    int zi = blockIdx.z, g = slab0 + zi;
    int b = g >> 3, h = g & 7;
    int j0 = blockIdx.x * 64, m0 = blockIdx.y * 64;
    __shared__ float Qs[64][68];   // [k][m]
    __shared__ float Ks[64][68];   // [k][j]
    int t = threadIdx.x;
    int lr = t >> 4, lc = (t & 15) * 4;
    const float* Qb = ql + ((size_t)g * MM + m0) * DH;
    const float* Kb = qkv + (size_t)b * SEQ * 1536 + D + h * DH;
    #pragma unroll
    for (int r = 0; r < 4; r++) {
        int row = lr + r * 16;
        float4 q4 = *(const float4*)(Qb + (size_t)row * DH + lc);
        Qs[lc+0][row] = q4.x; Qs[lc+1][row] = q4.y; Qs[lc+2][row] = q4.z; Qs[lc+3][row] = q4.w;
        float4 k4 = *(const float4*)(Kb + (size_t)(j0 + row) * 1536 + lc);
        Ks[lc+0][row] = k4.x; Ks[lc+1][row] = k4.y; Ks[lc+2][row] = k4.z; Ks[lc+3][row] = k4.w;
    }
    __syncthreads();
    int tm = t >> 4, tn = t & 15;
    float acc[4][4] = {};
    #pragma unroll 8
    for (int kk = 0; kk < 64; kk++) {
        float4 a = *(const float4*)&Qs[kk][tm*4];
        float4 bv = *(const float4*)&Ks[kk][tn*4];
        float avv[4] = {a.x,a.y,a.z,a.w};
        float bvv[4] = {bv.x,bv.y,bv.z,bv.w};
        #pragma unroll
        for (int i = 0; i < 4; i++)
            #pragma unroll
            for (int j = 0; j < 4; j++)
                acc[i][j] = fmaf(avv[i], bvv[j], acc[i][j]);
    }
    float* Cb = s3 + (size_t)zi * MM * SEQ + (size_t)m0 * SEQ + j0;
    #pragma unroll
    for (int i = 0; i < 4; i++)
        *(float4*)(Cb + (size_t)(tm*4+i) * SEQ + tn*4) =
            make_float4(acc[i][0], acc[i][1], acc[i][2], acc[i][3]);
}

// in-place row softmax over SEQ
__global__ __launch_bounds__(256)
void s3_softmax(float* __restrict__ s3)
{
    float* row = s3 + (size_t)blockIdx.x * SEQ;
    int t = threadIdx.x;
    __shared__ float red[256];
    float mx = -3.4e38f;
    for (int j = t; j < SEQ; j += 256) mx = fmaxf(mx, row[j]);
    red[t] = mx; __syncthreads();
    for (int o = 128; o > 0; o >>= 1) { if (t < o) red[t] = fmaxf(red[t], red[t+o]); __syncthreads(); }
    mx = red[0]; __syncthreads();
    float sum = 0.f;
    for (int j = t; j < SEQ; j += 256) { float e = expf(row[j] - mx); row[j] = e; sum += e; }
    red[t] = sum; __syncthreads();
    for (int o = 128; o > 0; o >>= 1) { if (t < o) red[t] += red[t+o]; __syncthreads(); }
    float inv = 1.0f / red[0];
    for (int j = t; j < SEQ; j += 256) row[j] *= inv;
}

// P scores: P[zi] (SEQ x MM) = q @ k_l^T  (q rows from QKV, klt is [d][m])
__global__ __launch_bounds__(256)
void qp_scores(const float* __restrict__ qkv, const float* __restrict__ klt,
               float* __restrict__ P, int slab0)
{
    int zi = blockIdx.z, g = slab0 + zi;
    int b = g >> 3, h = g & 7;
    int j0 = blockIdx.x * 64, m0 = blockIdx.y * 64;
    __shared__ float Qs[64][68];   // [k][token]
    __shared__ float Ks[64][68];   // [k][j]
    int t = threadIdx.x;
    int lr = t >> 4, lc = (t & 15) * 4;
    const float* Qb = qkv + ((size_t)b * SEQ + m0) * 1536 + h * DH;
    const float* Kb = klt + (size_t)g * DH * MM;
    #pragma unroll
    for (int r = 0; r < 4; r++) {
        int row = lr + r * 16;
        float4 q4 = *(const float4*)(Qb + (size_t)row * 1536 + lc);
        Qs[lc+0][row] = q4.x; Qs[lc+1][row] = q4.y; Qs[lc+2][row] = q4.z; Qs[lc+3][row] = q4.w;
        float4 k4 = *(const float4*)(Kb + (size_t)row * MM + j0 + lc);   // row = d
        *(float4*)&Ks[row][lc] = k4;
    }
    __syncthreads();
    int tm = t >> 4, tn = t & 15;
    float acc[4][4] = {};
    #pragma unroll 8
    for (int kk = 0; kk < 64; kk++) {
        float4 a = *(const float4*)&Qs[kk][tm*4];
        float4 bv = *(const float4*)&Ks[kk][tn*4];
        float avv[4] = {a.x,a.y,a.z,a.w};
        float bvv[4] = {bv.x,bv.y,bv.z,bv.w};
        #pragma unroll
        for (int i = 0; i < 4; i++)
            #pragma unroll
            for (int j = 0; j < 4; j++)
                acc[i][j] = fmaf(avv[i], bvv[j], acc[i][j]);
    }
    float* Cb = P + (size_t)zi * SEQ * MM + (size_t)m0 * MM + j0;
    #pragma unroll
    for (int i = 0; i < 4; i++)
        *(float4*)(Cb + (size_t)(tm*4+i) * MM + tn*4) =
            make_float4(acc[i][0], acc[i][1], acc[i][2], acc[i][3]);
}

// softmax over 256 contiguous elems; 1 wave per row, 4 rows per block
__global__ __launch_bounds__(256)
void softmax256(float* __restrict__ P)
{
    int wid = threadIdx.x >> 6, lane = threadIdx.x & 63;
    float* p = P + ((size_t)blockIdx.x * 4 + wid) * MM + lane * 4;
    float4 v = *(float4*)p;
    float m = fmaxf(fmaxf(v.x, v.y), fmaxf(v.z, v.w));
    for (int o = 32; o > 0; o >>= 1) m = fmaxf(m, __shfl_xor(m, o));
    v.x = expf(v.x - m); v.y = expf(v.y - m);
    v.z = expf(v.z - m); v.w = expf(v.w - m);
    float s = v.x + v.y + v.z + v.w;
    for (int o = 32; o > 0; o >>= 1) s += __shfl_xor(s, o);
    float inv = 1.0f / s;
    v.x *= inv; v.y *= inv; v.z *= inv; v.w *= inv;
    *(float4*)p = v;
}

// depthwise 33x1 conv over sequence of v, added into attn; 16 tokens/block
__global__ __launch_bounds__(512)
void res_add(const float* __restrict__ qkv, const float* __restrict__ rw,
             float* __restrict__ attn)
{
    int blk = blockIdx.x;
    int b = blk / (SEQ/16), i0 = (blk % (SEQ/16)) * 16;
    int c = threadIdx.x, h = c >> 6;
    __shared__ float w[NH*33];
    if (c < NH*33) w[c] = rw[c];
    __syncthreads();
    float acc[16];
    float* ab = attn + ((size_t)b * SEQ + i0) * D + c;
    #pragma unroll
    for (int r = 0; r < 16; r++) acc[r] = ab[(size_t)r * D];
    const float* vb = qkv + (size_t)b * SEQ * 1536 + 2*D + c;
    const float* wh = w + h * 33;
    #pragma unroll 4
    for (int jj = 0; jj < 48; jj++) {
        int j = i0 + jj - 16;
        float val = ((unsigned)j < (unsigned)SEQ) ? vb[(size_t)j * 1536] : 0.f;
        #pragma unroll
        for (int r = 0; r < 16; r++) {
            int ky = jj - r;
            if (ky >= 0 && ky < 33) acc[r] = fmaf(val, wh[ky], acc[r]);
        }
    }
    #pragma unroll
    for (int r = 0; r < 16; r++) ab[(size_t)r * D] = acc[r];
}

// ---------------------------------------------------------------- PPEG
// transpose H feat (pos-major, c contiguous) -> planes (c-major, pos contiguous)
__global__ __launch_bounds__(256)
void t_fw(const float* __restrict__ H, float* __restrict__ P)
{
    __shared__ float tile[32][33];
    int p0 = blockIdx.x * 32, c0 = blockIdx.y * 32, b = blockIdx.z;
    int tx = threadIdx.x & 31, ty = threadIdx.x >> 5;
    #pragma unroll
    for (int k = 0; k < 4; k++) {
        int pos = p0 + ty + k*8;
        tile[ty + k*8][tx] = (pos < 10000)
            ? H[((size_t)b * NTOK + 1 + pos) * D + c0 + tx] : 0.f;
    }
    __syncthreads();
    #pragma unroll
    for (int k = 0; k < 4; k++) {
        int c = c0 + ty + k*8, pos = p0 + tx;
        if (pos < 10000)
            P[((size_t)b * D + c) * 10000 + pos] = tile[tx][ty + k*8];
    }
}

// per-plane conv in LDS with zero halo: y = x + dw7+b7 + dw5+b5 + dw3+b3
__global__ __launch_bounds__(256)
void ppeg_conv(const float* __restrict__ P,
               const float* __restrict__ w7, const float* __restrict__ b7,
               const float* __restrict__ w5, const float* __restrict__ b5,
               const float* __restrict__ w3, const float* __restrict__ b3,
               float* __restrict__ Q)
{
    __shared__ float PS[106 * 107];  // (100+2*3) x (100+6+1 pad), zero halo
    __shared__ float w7s[49], w5s[25], w3s[9];
    int blk = blockIdx.x;
    int b = blk >> 9, c = blk & 511;
    int t = threadIdx.x;
    for (int idx = t; idx < 106*107; idx += 256) PS[idx] = 0.f;
    if (t < 49) w7s[t] = w7[(size_t)c * 49 + t];
    if (t < 25) w5s[t] = w5[(size_t)c * 25 + t];
    if (t < 9)  w3s[t] = w3[(size_t)c * 9 + t];
    float bsum = b7[c] + b5[c] + b3[c];
    __syncthreads();
    const float* Pin = P + ((size_t)b * D + c) * 10000;
    for (int p = t; p < 10000; p += 256) {
        int y = p / 100, x = p - y * 100;
        PS[(y + 3) * 107 + x + 3] = Pin[p];
    }
    __syncthreads();
    float* Qo = Q + ((size_t)b * D + c) * 10000;
    for (int p = t; p < 10000; p += 256) {
        int y = p / 100, x = p - y * 100;
        int base = (y + 3) * 107 + x + 3;
        float acc = PS[base] + bsum;
        #pragma unroll
        for (int ky = 0; ky < 7; ky++)
            #pragma unroll
            for (int kx = 0; kx < 7; kx++)
                acc = fmaf(PS[base + (ky-3)*107 + (kx-3)], w7s[ky*7+kx], acc);
        #pragma unroll
        for (int ky = 0; ky < 5; ky++)
            #pragma unroll
            for (int kx = 0; kx < 5; kx++)
                acc = fmaf(PS[base + (ky-2)*107 + (kx-2)], w5s[ky*5+kx], acc);
        #pragma unroll
        for (int ky = 0; ky < 3; ky++)
            #pragma unroll
            for (int kx = 0; kx < 3; kx++)
                acc = fmaf(PS[base + (ky-1)*107 + (kx-1)], w3s[ky*3+kx], acc);
        Qo[p] = acc;
    }
}

// transpose planes back into H feat region
__global__ __launch_bounds__(256)
void t_bw(const float* __restrict__ Q, float* __restrict__ H)
{
    __shared__ float tile[32][33];
    int p0 = blockIdx.x * 32, c0 = blockIdx.y * 32, b = blockIdx.z;
    int tx = threadIdx.x & 31, ty = threadIdx.x >> 5;
    #pragma unroll
    for (int k = 0; k < 4; k++) {
        int c = c0 + ty + k*8, pos = p0 + tx;
        tile[ty + k*8][tx] = (pos < 10000)
            ? Q[((size_t)b * D + c) * 10000 + pos] : 0.f;
    }
    __syncthreads();
    #pragma unroll
    for (int k = 0; k < 4; k++) {
        int pos = p0 + ty + k*8;
        if (pos < 10000)
            H[((size_t)b * NTOK + 1 + pos) * D + c0 + tx] = tile[tx][ty + k*8];
    }
}

// final: LN(row0) @ w_fc2 + b ; softmax ; argmax -> 10 floats
__global__ __launch_bounds__(512)
void final_head(const float* __restrict__ H, const float* __restrict__ g,
                const float* __restrict__ bt, const float* __restrict__ w2,
                const float* __restrict__ b2, float* __restrict__ out)
{
    int b = blockIdx.x, t = threadIdx.x;
    __shared__ float red[512];
    float v = H[(size_t)b * NTOK * D + t];
    red[t] = v; __syncthreads();
    for (int o = 256; o > 0; o >>= 1) { if (t < o) red[t] += red[t+o]; __syncthreads(); }
    float mu = red[0] * (1.0f / D); __syncthreads();
    float dv = v - mu;
    red[t] = dv*dv; __syncthreads();
    for (int o = 256; o > 0; o >>= 1) { if (t < o) red[t] += red[t+o]; __syncthreads(); }
    float rstd = rsqrtf(red[0] * (1.0f / D) + EPS_); __syncthreads();
    float xn = dv * rstd * g[t] + bt[t];
    red[t] = xn * w2[2*t]; __syncthreads();
    for (int o = 256; o > 0; o >>= 1) { if (t < o) red[t] += red[t+o]; __syncthreads(); }
    float l0 = red[0] + b2[0]; __syncthreads();
    red[t] = xn * w2[2*t+1]; __syncthreads();
    for (int o = 256; o > 0; o >>= 1) { if (t < o) red[t] += red[t+o]; __syncthreads(); }
    float l1 = red[0] + b2[1];
    if (t == 0) {
        out[b*2+0] = l0; out[b*2+1] = l1;
        float mx = fmaxf(l0, l1);
        float e0 = expf(l0 - mx), e1 = expf(l1 - mx);
        float ssum = e0 + e1;
        out[4 + b*2 + 0] = e0 / ssum;
        out[4 + b*2 + 1] = e1 / ssum;
        out[8 + b] = (l1 > l0) ? 1.0f : 0.0f;
    }
}

// ---------------------------------------------------------------------------
extern "C" void kernel_launch(void* const* d_in, const int* in_sizes, int n_in,
                              void* d_out, int out_size, void* d_ws, size_t ws_size,
                              hipStream_t stream)
{
    const float* x      = (const float*)d_in[0];
    const float* w_fc1  = (const float*)d_in[1];
    const float* b_fc1  = (const float*)d_in[2];
    const float* cls    = (const float*)d_in[3];
    const float* ln1_g  = (const float*)d_in[4];
    const float* ln1_b  = (const float*)d_in[5];
    const float* qkv1_w = (const float*)d_in[6];
    const float* out1_w = (const float*)d_in[7];
    const float* out1_b = (const float*)d_in[8];
    const float* res1_w = (const float*)d_in[9];
    const float* ln2_g  = (const float*)d_in[10];
    const float* ln2_b  = (const float*)d_in[11];
    const float* qkv2_w = (const float*)d_in[12];
    const float* out2_w = (const float*)d_in[13];
    const float* out2_b = (const float*)d_in[14];
    const float* res2_w = (const float*)d_in[15];
    const float* pw7 = (const float*)d_in[16];
    const float* pb7 = (const float*)d_in[17];
    const float* pw5 = (const float*)d_in[18];
    const float* pb5 = (const float*)d_in[19];
    const float* pw3 = (const float*)d_in[20];
    const float* pb3 = (const float*)d_in[21];
    const float* lnf_g = (const float*)d_in[22];
    const float* lnf_b = (const float*)d_in[23];
    const float* w_fc2 = (const float*)d_in[24];
    const float* b_fc2 = (const float*)d_in[25];

    float* ws = (float*)d_ws;
    size_t off = 0;
    auto alloc = [&](size_t n) { float* p = ws + off; off += (n + 63) & ~(size_t)63; return p; };
    float* H    = alloc((size_t)BB * NTOK * D);
    float* LN   = alloc((size_t)BB * SEQ * D);
    float* QKV  = alloc((size_t)BB * SEQ * 3 * D);
    float* QL   = alloc((size_t)BB * NH * MM * DH);
    float* KLT  = alloc((size_t)BB * NH * DH * MM);
    float* A2   = alloc((size_t)BB * NH * MM * MM);
    float* ZA   = alloc((size_t)BB * NH * MM * MM);
    float* ZB   = alloc((size_t)BB * NH * MM * MM);
    float* XZ   = alloc((size_t)BB * NH * MM * MM);
    float* T1   = alloc((size_t)BB * NH * MM * MM);
    float* T2   = alloc((size_t)BB * NH * MM * MM);
    float* A3V  = alloc((size_t)BB * NH * MM * DH);
    float* WB   = alloc((size_t)BB * NH * MM * DH);
    float* S3   = alloc((size_t)8 * MM * SEQ);       // also: P-buffer, ppeg planes
    float* SCR  = alloc(64);
    float* ATTN = LN;
    (void)ws_size; (void)in_sizes; (void)n_in; (void)out_size;

    // 1) h = relu(x @ w_fc1 + b_fc1)
    for (int b = 0; b < BB; b++) {
        dim3 g(D/128, (N0 + 127)/128);
        sgemm128<<<g, 256, 0, stream>>>(x + (size_t)b*N0*DIN, w_fc1,
            H + ((size_t)b*NTOK + 1)*D, b_fc1,
            N0, D, DIN, DIN, D, D, FLAG_BIAS|FLAG_RELU, 0, 1.f);
    }
    fill_cls<<<BB, D, 0, stream>>>(cls, H);

    auto attention = [&](const float* lg, const float* lb, const float* qw,
                         const float* ow, const float* ob, const float* rw)
    {
        ln_pad<<<BB*SEQ, 256, 0, stream>>>(H, lg, lb, LN);
        { dim3 g((3*D)/128, (BB*SEQ)/128);
          sgemm128<<<g, 256, 0, stream>>>(LN, qw, QKV, nullptr,
              BB*SEQ, 3*D, D, D, 3*D, 3*D, 0, D, 0.125f); }
        landmarks<<<BB*MM, 512, 0, stream>>>(QKV, QL, KLT);
        s2_softmax<<<BB*NH*MM, 256, 0, stream>>>(QL, KLT, A2);
        zero_scr<<<1, 64, 0, stream>>>(SCR);
        a2_alpha<<<BB*NH, 256, 0, stream>>>(A2, SCR);
        z_init<<<BB*NH*MM*MM/256, 256, 0, stream>>>(A2, SCR, ZA);
        float* z = ZA; float* zn = ZB;
        for (int it = 0; it < 6; it++) {
            dim3 g(4, 4, 16);
            bgemm<<<g,256,0,stream>>>(A2, 65536LL, MM,  z, 8LL*65536, 65536LL, MM,
                                      XZ, 8LL*65536, 65536LL, MM, MM, MM, MM, 0.f, 1.f, 1.f, 0);
            bgemm<<<g,256,0,stream>>>(XZ, 65536LL, MM,  XZ, 8LL*65536, 65536LL, MM,
                                      T1, 8LL*65536, 65536LL, MM, MM, MM, MM, 7.f, -1.f, 1.f, 0);
            bgemm<<<g,256,0,stream>>>(XZ, 65536LL, MM,  T1, 8LL*65536, 65536LL, MM,
                                      T2, 8LL*65536, 65536LL, MM, MM, MM, MM, 15.f, -1.f, 1.f, 0);
            bgemm<<<g,256,0,stream>>>(z, 65536LL, MM,  T2, 8LL*65536, 65536LL, MM,
                                      zn, 8LL*65536, 65536LL, MM, MM, MM, MM, 13.f, -1.f, 0.25f, 0);
            float* tsw = z; z = zn; zn = tsw;
        }
        // s3 pipeline -> A3V (split-K atomics), 8 slabs per group
        for (int grp = 0; grp < 2; grp++) {
            int slab0 = grp * 8;
            s3_scores<<<dim3(SEQ/64, MM/64, 8), 256, 0, stream>>>(QL, QKV, S3, slab0);
            s3_softmax<<<8*MM, 256, 0, stream>>>(S3);
            hipMemsetAsync(A3V + (size_t)slab0 * MM * DH, 0,
                           (size_t)8 * MM * DH * sizeof(float), stream);
            a3v_sk<<<dim3(1, MM/64, 8*16), 256, 0, stream>>>(S3, QKV, A3V, slab0);
        }
        // WB = z @ A3V
        bgemm<<<dim3(1, MM/64, 16), 256, 0, stream>>>(
            z, 65536LL, MM,
            A3V, 8LL*MM*DH, (long long)MM*DH, DH,
            WB, 8LL*MM*DH, (long long)MM*DH, DH,
            MM, DH, MM, 0.f, 1.f, 1.f, 0);
        // a1 pipeline: P = softmax(q@kl^T); ATTN = P @ WB
        for (int grp = 0; grp < 2; grp++) {
            int slab0 = grp * 8;
            qp_scores<<<dim3(MM/64, SEQ/64, 8), 256, 0, stream>>>(QKV, KLT, S3, slab0);
            softmax256<<<8*SEQ/4, 256, 0, stream>>>(S3);
            bgemm<<<dim3(1, SEQ/64, 8), 256, 0, stream>>>(
                S3, (long long)SEQ*MM, MM,
                WB, 8LL*MM*DH, (long long)MM*DH, DH,
                ATTN, (long long)SEQ*D, 64LL, D,
                SEQ, DH, MM, 0.f, 1.f, 1.f, slab0);
        }
        res_add<<<BB*SEQ/16, 512, 0, stream>>>(QKV, rw, ATTN);
        for (int b = 0; b < BB; b++) {
            dim3 g(D/128, (NTOK + 127)/128);
            sgemm128<<<g, 256, 0, stream>>>(ATTN + ((size_t)b*SEQ + PADR)*D, ow,
                H + (size_t)b*NTOK*D, ob,
                NTOK, D, D, D, D, D, FLAG_BIAS|FLAG_ACC, 0, 1.f);
        }
    };

    attention(ln1_g, ln1_b, qkv1_w, out1_w, out1_b, res1_w);

    // PPEG via channel-plane transposes (planes live inside S3 buffer)
    {
        float* Pp = S3;
        float* Qp = S3 + (size_t)BB * D * 10000;
        dim3 tg((10000 + 31)/32, D/32, BB);
        t_fw<<<tg, 256, 0, stream>>>(H, Pp);
        ppeg_conv<<<BB*D, 256, 0, stream>>>(Pp, pw7, pb7, pw5, pb5, pw3, pb3, Qp);
        t_bw<<<tg, 256, 0, stream>>>(Qp, H);
    }

    attention(ln2_g, ln2_b, qkv2_w, out2_w, out2_b, res2_w);

    final_head<<<BB, 512, 0, stream>>>(H, lnf_g, lnf_b, w_fc2, b_fc2, (float*)d_out);
}

// Round 4
// 2914.159 us; speedup vs baseline: 3.3437x; 1.4263x over previous
//
#include <hip/hip_runtime.h>
#include <math.h>

#define FLAG_RELU 1
#define FLAG_BIAS 2
#define FLAG_ACC  4
#define FLAG_ATOMIC 8

static constexpr int BB   = 2;
static constexpr int N0   = 10000;
static constexpr int DIN  = 1024;
static constexpr int D    = 512;
static constexpr int NH   = 8;
static constexpr int DH   = 64;
static constexpr int MM   = 256;
static constexpr int SEQ  = 10240;
static constexpr int PADR = 239;
static constexpr int NTOK = 10001;
static constexpr int LL   = 40;
static constexpr float EPS_ = 1e-5f;

typedef short short8v __attribute__((ext_vector_type(8)));
typedef float f32x4 __attribute__((ext_vector_type(4)));

__device__ __forceinline__ void atomicMaxPosF(float* addr, float v) {
    atomicMax((unsigned int*)addr, __float_as_uint(v));
}
__device__ __forceinline__ ushort f2bf(float f) {
    unsigned u = __float_as_uint(f);
    return (ushort)((u + 0x7FFFu + ((u >> 16) & 1u)) >> 16);
}
__device__ __forceinline__ float bf2f(ushort h) {
    return __uint_as_float(((unsigned)h) << 16);
}
__device__ __forceinline__ void split4(float4 f, ushort* ph, ushort* pl) {
    ushort4 hv, lv;
    hv.x = f2bf(f.x); lv.x = f2bf(f.x - bf2f(hv.x));
    hv.y = f2bf(f.y); lv.y = f2bf(f.y - bf2f(hv.y));
    hv.z = f2bf(f.z); lv.z = f2bf(f.z - bf2f(hv.z));
    hv.w = f2bf(f.w); lv.w = f2bf(f.w - bf2f(hv.w));
    *(ushort4*)ph = hv; *(ushort4*)pl = lv;
}

// ------------------------------------------------------- MFMA GEMM 128x128
// C = op(A @ B); A fp32 (MxK, lda, M guarded), B pre-split bf16T (NxK, ldbt).
// N mult of 128, K mult of 32. 3-pass split bf16 -> ~fp32 precision.
__global__ __launch_bounds__(256)
void mgemm128(const float* __restrict__ A, int lda,
              const ushort* __restrict__ BtH, const ushort* __restrict__ BtL, int ldbt,
              float* __restrict__ C, int ldc, const float* __restrict__ bias,
              int M, int N, int K, int flags, int qcols, float qscale)
{
    __shared__ ushort AsH[128*40], AsL[128*40], BsH[128*40], BsL[128*40];
    int t = threadIdx.x;
    int m0 = blockIdx.y * 128, n0 = blockIdx.x * 128;
    int w = t >> 6, lane = t & 63, q = lane >> 4, r = lane & 15;
    int wm = w >> 1, wn = w & 1;
    f32x4 acc[4][4];
    #pragma unroll
    for (int i = 0; i < 4; i++)
        #pragma unroll
        for (int j = 0; j < 4; j++) acc[i][j] = (f32x4){0.f,0.f,0.f,0.f};

    int srow = t >> 1, scg = (t & 1) * 16;
    for (int k0 = 0; k0 < K; k0 += 32) {
        {   // stage A (fp32 -> hi/lo)
            int gm = m0 + srow;
            float4 f0 = {0,0,0,0}, f1 = {0,0,0,0}, f2 = {0,0,0,0}, f3 = {0,0,0,0};
            if (gm < M) {
                const float* ap = A + (size_t)gm * lda + k0 + scg;
                f0 = *(const float4*)(ap); f1 = *(const float4*)(ap+4);
                f2 = *(const float4*)(ap+8); f3 = *(const float4*)(ap+12);
            }
            int o = srow*40 + scg;
            split4(f0, &AsH[o],    &AsL[o]);
            split4(f1, &AsH[o+4],  &AsL[o+4]);
            split4(f2, &AsH[o+8],  &AsL[o+8]);
            split4(f3, &AsH[o+12], &AsL[o+12]);
        }
        {   // stage B (pure bf16 copy)
            size_t gb = (size_t)(n0 + srow) * ldbt + k0 + scg;
            int o = srow*40 + scg;
            *(uint4*)&BsH[o]   = *(const uint4*)(BtH + gb);
            *(uint4*)&BsH[o+8] = *(const uint4*)(BtH + gb + 8);
            *(uint4*)&BsL[o]   = *(const uint4*)(BtL + gb);
            *(uint4*)&BsL[o+8] = *(const uint4*)(BtL + gb + 8);
        }
        __syncthreads();
        short8v ah[4], al[4];
        #pragma unroll
        for (int mi = 0; mi < 4; mi++) {
            int row = wm*64 + mi*16 + r;
            ah[mi] = *(const short8v*)&AsH[row*40 + q*8];
            al[mi] = *(const short8v*)&AsL[row*40 + q*8];
        }
        #pragma unroll
        for (int ni = 0; ni < 4; ni++) {
            int col = wn*64 + ni*16 + r;
            short8v bh = *(const short8v*)&BsH[col*40 + q*8];
            short8v bl = *(const short8v*)&BsL[col*40 + q*8];
            #pragma unroll
            for (int mi = 0; mi < 4; mi++) {
                acc[mi][ni] = __builtin_amdgcn_mfma_f32_16x16x32_bf16(ah[mi], bh, acc[mi][ni], 0,0,0);
                acc[mi][ni] = __builtin_amdgcn_mfma_f32_16x16x32_bf16(ah[mi], bl, acc[mi][ni], 0,0,0);
                acc[mi][ni] = __builtin_amdgcn_mfma_f32_16x16x32_bf16(al[mi], bh, acc[mi][ni], 0,0,0);
            }
        }
        __syncthreads();
    }
    #pragma unroll
    for (int mi = 0; mi < 4; mi++)
        #pragma unroll
        for (int ni = 0; ni < 4; ni++) {
            int gcol = n0 + wn*64 + ni*16 + r;
            float qs = (gcol < qcols) ? qscale : 1.f;
            float bv = (flags & FLAG_BIAS) ? bias[gcol] : 0.f;
            #pragma unroll
            for (int rg = 0; rg < 4; rg++) {
                int grow = m0 + wm*64 + mi*16 + q*4 + rg;
                if (grow >= M) continue;
                float v = acc[mi][ni][rg] * qs + bv;
                if (flags & FLAG_RELU) v = fmaxf(v, 0.f);
                float* cp = C + (size_t)grow * ldc + gcol;
                if (flags & FLAG_ACC) v += *cp;
                *cp = v;
            }
        }
}

// ------------------------------------------------------- MFMA batched 64x64
// slab g = slab0 + zi; b=g>>3, h=g&7; zi = blockIdx.z/nchunk, chunk = %.
// A fp32: Abase + b*sAb + h*sAh + zi*sAz (MxK, lda)
// B: if Bnt: fp32 NT (NxK, ldb) stage-convert; else pre-split bf16 BtH/L.
// C = osc*(bsc*(A@B) + dg*A[m][n]); C store skipped when Cbase==nullptr;
// optional atomicAdd; optional transposed bf16 hi/lo emit to eTH/eTL.
__global__ __launch_bounds__(256)
void mbgemm64(const float* __restrict__ Abase, long long sAb, long long sAh, long long sAz, int lda,
              const ushort* __restrict__ BtH, const ushort* __restrict__ BtL,
              const float* __restrict__ Bnt, long long sBb, long long sBh, int ldb,
              float* __restrict__ Cbase, long long sCb, long long sCh, long long sCz, int ldc,
              ushort* __restrict__ eTH, ushort* __restrict__ eTL, long long sT, int ldct,
              int M, int N, int K, int nchunk,
              float dg, float bsc, float osc, int slab0, int flags)
{
    __shared__ ushort AsH[64*40], AsL[64*40], BsH[64*40], BsL[64*40];
    int zi = blockIdx.z / nchunk, ch = blockIdx.z % nchunk;
    int g = slab0 + zi, b = g >> 3, h = g & 7;
    const float* A = Abase + (size_t)b*sAb + (size_t)h*sAh + (size_t)zi*sAz;
    float* C = Cbase ? (Cbase + (size_t)b*sCb + (size_t)h*sCh + (size_t)zi*sCz) : nullptr;
    int kpc = K / nchunk;
    int kb = ch * kpc, ke = kb + kpc;
    int t = threadIdx.x;
    int m0 = blockIdx.y * 64, n0 = blockIdx.x * 64;
    int w = t >> 6, lane = t & 63, q = lane >> 4, r = lane & 15;
    int wm = w >> 1, wn = w & 1;
    f32x4 acc[2][2];
    #pragma unroll
    for (int i = 0; i < 2; i++)
        #pragma unroll
        for (int j = 0; j < 2; j++) acc[i][j] = (f32x4){0.f,0.f,0.f,0.f};

    int srow = t >> 2, scg = (t & 3) * 8;
    for (int k0 = kb; k0 < ke; k0 += 32) {
        {   // A stage-convert
            const float* ap = A + (size_t)(m0 + srow) * lda + k0 + scg;
            float4 f0 = *(const float4*)ap, f1 = *(const float4*)(ap+4);
            int o = srow*40 + scg;
            split4(f0, &AsH[o],   &AsL[o]);
            split4(f1, &AsH[o+4], &AsL[o+4]);
        }
        if (Bnt) {
            const float* bp = Bnt + (size_t)b*sBb + (size_t)h*sBh
                            + (size_t)(n0 + srow) * ldb + k0 + scg;
            float4 f0 = *(const float4*)bp, f1 = *(const float4*)(bp+4);
            int o = srow*40 + scg;
            split4(f0, &BsH[o],   &BsL[o]);
            split4(f1, &BsH[o+4], &BsL[o+4]);
        } else {
            size_t gb = (size_t)b*sBb + (size_t)h*sBh + (size_t)(n0 + srow) * ldb + k0 + scg;
            int o = srow*40 + scg;
            *(uint4*)&BsH[o] = *(const uint4*)(BtH + gb);
            *(uint4*)&BsL[o] = *(const uint4*)(BtL + gb);
        }
        __syncthreads();
        short8v ah[2], al[2];
        #pragma unroll
        for (int mi = 0; mi < 2; mi++) {
            int row = wm*32 + mi*16 + r;
            ah[mi] = *(const short8v*)&AsH[row*40 + q*8];
            al[mi] = *(const short8v*)&AsL[row*40 + q*8];
        }
        #pragma unroll
        for (int ni = 0; ni < 2; ni++) {
            int col = wn*32 + ni*16 + r;
            short8v bh = *(const short8v*)&BsH[col*40 + q*8];
            short8v bl = *(const short8v*)&BsL[col*40 + q*8];
            #pragma unroll
            for (int mi = 0; mi < 2; mi++) {
                acc[mi][ni] = __builtin_amdgcn_mfma_f32_16x16x32_bf16(ah[mi], bh, acc[mi][ni], 0,0,0);
                acc[mi][ni] = __builtin_amdgcn_mfma_f32_16x16x32_bf16(ah[mi], bl, acc[mi][ni], 0,0,0);
                acc[mi][ni] = __builtin_amdgcn_mfma_f32_16x16x32_bf16(al[mi], bh, acc[mi][ni], 0,0,0);
            }
        }
        __syncthreads();
    }
    bool dgnz = (dg != 0.f);
    #pragma unroll
    for (int mi = 0; mi < 2; mi++)
        #pragma unroll
        for (int ni = 0; ni < 2; ni++) {
            int gm0 = m0 + wm*32 + mi*16 + q*4;
            int gn  = n0 + wn*32 + ni*16 + r;
            float v[4];
            #pragma unroll
            for (int rg = 0; rg < 4; rg++) {
                float u = bsc * acc[mi][ni][rg];
                if (dgnz) u += dg * A[(size_t)(gm0+rg) * lda + gn];
                v[rg] = osc * u;
            }
            if (C) {
                if (flags & FLAG_ATOMIC) {
                    #pragma unroll
                    for (int rg = 0; rg < 4; rg++)
                        atomicAdd(C + (size_t)(gm0+rg) * ldc + gn, v[rg]);
                } else {
                    #pragma unroll
                    for (int rg = 0; rg < 4; rg++)
                        C[(size_t)(gm0+rg) * ldc + gn] = v[rg];
                }
            }
            if (eTH) {
                ushort4 hv, lv;
                hv.x = f2bf(v[0]); lv.x = f2bf(v[0] - bf2f(hv.x));
                hv.y = f2bf(v[1]); lv.y = f2bf(v[1] - bf2f(hv.y));
                hv.z = f2bf(v[2]); lv.z = f2bf(v[2] - bf2f(hv.z));
                hv.w = f2bf(v[3]); lv.w = f2bf(v[3] - bf2f(hv.w));
                size_t to = (size_t)g * sT + (size_t)gn * ldct + gm0;
                *(ushort4*)(eTH + to) = hv;
                *(ushort4*)(eTL + to) = lv;
            }
        }
}

// ---------------------------------- transpose + split fp32 (RxC) -> bf16 (CxR)
__global__ __launch_bounds__(256)
void convsplitT(const float* __restrict__ in, ushort* __restrict__ oh, ushort* __restrict__ ol,
                int R, int C, int ldin, long long sInB, long long sInH, long long sInZ,
                int ldo, long long sOutZ)
{
    __shared__ float tile[32][33];
    int z = blockIdx.z, b = z >> 3, h = z & 7;
    const float* I = in + (size_t)b*sInB + (size_t)h*sInH + (size_t)z*sInZ;
    int p0 = blockIdx.x * 32, c0 = blockIdx.y * 32;
    int tx = threadIdx.x & 31, ty = threadIdx.x >> 5;
    #pragma unroll
    for (int k = 0; k < 4; k++) {
        int rr = p0 + ty + k*8, cc = c0 + tx;
        tile[ty + k*8][tx] = (rr < R && cc < C) ? I[(size_t)rr * ldin + cc] : 0.f;
    }
    __syncthreads();
    #pragma unroll
    for (int k = 0; k < 4; k++) {
        int rr = p0 + tx, cc = c0 + ty + k*8;
        if (rr < R && cc < C) {
            float f = tile[tx][ty + k*8];
            ushort hv = f2bf(f);
            size_t o = (size_t)z * sOutZ + (size_t)cc * ldo + rr;
            oh[o] = hv; ol[o] = f2bf(f - bf2f(hv));
        }
    }
}

// ---------------------------------------------------------------- small ops
__global__ void fill_cls(const float* __restrict__ cls, float* __restrict__ H) {
    H[(size_t)blockIdx.x * NTOK * D + threadIdx.x] = cls[threadIdx.x];
}

__global__ __launch_bounds__(256)
void ln_pad(const float* __restrict__ H, const float* __restrict__ g,
            const float* __restrict__ bt, float* __restrict__ out)
{
    int blk = blockIdx.x;
    int b = blk / SEQ, i = blk % SEQ;
    int t = threadIdx.x;
    float* orow = out + (size_t)blk * D;
    if (i < PADR) { orow[t] = 0.f; orow[t+256] = 0.f; return; }
    const float* x = H + ((size_t)b * NTOK + (i - PADR)) * D;
    float v0 = x[t], v1 = x[t+256];
    __shared__ float w1[4], w2[4];
    float s = v0 + v1;
    for (int o = 32; o > 0; o >>= 1) s += __shfl_xor(s, o);
    if ((t & 63) == 0) w1[t >> 6] = s;
    __syncthreads();
    float mu = (w1[0]+w1[1]+w1[2]+w1[3]) * (1.0f / D);
    float d0 = v0 - mu, d1 = v1 - mu;
    float qq = d0*d0 + d1*d1;
    for (int o = 32; o > 0; o >>= 1) qq += __shfl_xor(qq, o);
    if ((t & 63) == 0) w2[t >> 6] = qq;
    __syncthreads();
    float rs = rsqrtf((w2[0]+w2[1]+w2[2]+w2[3]) * (1.0f / D) + EPS_);
    orow[t]     = d0 * rs * g[t]     + bt[t];
    orow[t+256] = d1 * rs * g[t+256] + bt[t+256];
}

__global__ __launch_bounds__(512)
void landmarks(const float* __restrict__ qkv, float* __restrict__ ql,
               float* __restrict__ klt, ushort* __restrict__ klH, ushort* __restrict__ klL)
{
    int blk = blockIdx.x;
    int b = blk >> 8, m = blk & 255;
    int c = threadIdx.x;
    const float* base = qkv + ((size_t)b * SEQ + (size_t)m * LL) * 1536;
    float sq0=0,sq1=0,sq2=0,sq3=0, sk0=0,sk1=0,sk2=0,sk3=0;
    for (int tt = 0; tt < LL; tt += 4) {
        const float* rr = base + (size_t)tt * 1536;
        sq0 += rr[c];          sk0 += rr[512 + c];
        sq1 += rr[1536 + c];   sk1 += rr[1536 + 512 + c];
        sq2 += rr[3072 + c];   sk2 += rr[3072 + 512 + c];
        sq3 += rr[4608 + c];   sk3 += rr[4608 + 512 + c];
    }
    float sq = (sq0+sq1+sq2+sq3) * (1.0f / LL);
    float sk = (sk0+sk1+sk2+sk3) * (1.0f / LL);
    int h = c >> 6, d = c & 63;
    int slab = b * NH + h;
    ql [((size_t)slab * MM + m) * DH + d] = sq;
    klt[((size_t)slab * DH + d) * MM + m] = sk;
    size_t kidx = ((size_t)slab * MM + m) * DH + d;
    ushort kh = f2bf(sk);
    klH[kidx] = kh; klL[kidx] = f2bf(sk - bf2f(kh));
}

__global__ __launch_bounds__(256)
void s2_softmax(const float* __restrict__ ql, const float* __restrict__ klt,
                float* __restrict__ a2)
{
    int blk = blockIdx.x;
    int m = blk & 255, slab = blk >> 8;
    int j = threadIdx.x;
    __shared__ float q[64];
    __shared__ float red[256];
    if (j < 64) q[j] = ql[((size_t)slab * MM + m) * DH + j];
    __syncthreads();
    const float* kt = klt + (size_t)slab * DH * MM;
    float s = 0.f;
    #pragma unroll 8
    for (int kk = 0; kk < 64; kk++) s = fmaf(q[kk], kt[kk*MM + j], s);
    red[j] = s; __syncthreads();
    for (int o = 128; o > 0; o >>= 1) { if (j < o) red[j] = fmaxf(red[j], red[j+o]); __syncthreads(); }
    float mx = red[0]; __syncthreads();
    float e = expf(s - mx);
    red[j] = e; __syncthreads();
    for (int o = 128; o > 0; o >>= 1) { if (j < o) red[j] += red[j+o]; __syncthreads(); }
    a2[((size_t)slab * MM + m) * MM + j] = e / red[0];
}

__global__ void zero_scr(float* s) { if (threadIdx.x < 2) s[threadIdx.x] = 0.f; }

__global__ __launch_bounds__(256)
void a2_alpha(const float* __restrict__ a2, float* __restrict__ scr)
{
    int slab = blockIdx.x, t = threadIdx.x;
    const float* A = a2 + (size_t)slab * MM * MM;
    float cs = 0.f, rs = 0.f;
    for (int rr = 0; rr < MM; rr++) cs += fabsf(A[(size_t)rr * MM + t]);
    for (int cc = 0; cc < MM; cc++) rs += fabsf(A[(size_t)t * MM + cc]);
    __shared__ float red[256];
    red[t] = rs; __syncthreads();
    for (int o = 128; o > 0; o >>= 1) { if (t < o) red[t] = fmaxf(red[t], red[t+o]); __syncthreads(); }
    float mrs = red[0]; __syncthreads();
    red[t] = cs; __syncthreads();
    for (int o = 128; o > 0; o >>= 1) { if (t < o) red[t] = fmaxf(red[t], red[t+o]); __syncthreads(); }
    float mcs = red[0];
    if (t == 0) { atomicMaxPosF(scr + 0, mrs); atomicMaxPosF(scr + 1, mcs); }
}

// z = a2^T * inv (fp32) ; also emit zT = a2*inv as bf16 hi/lo
__global__ __launch_bounds__(256)
void z_init(const float* __restrict__ a2, const float* __restrict__ scr,
            float* __restrict__ z, ushort* __restrict__ zTh, ushort* __restrict__ zTl)
{
    size_t idx = (size_t)blockIdx.x * 256 + threadIdx.x;
    int slab = (int)(idx >> 16), rr = (int)((idx >> 8) & 255), cc = (int)(idx & 255);
    float inv = 1.0f / (scr[0] * scr[1]);
    z[idx] = a2[((size_t)slab << 16) + (size_t)cc * MM + rr] * inv;
    float tv = a2[idx] * inv;
    ushort th = f2bf(tv);
    zTh[idx] = th; zTl[idx] = f2bf(tv - bf2f(th));
}

__global__ __launch_bounds__(256)
void s3_softmax(float* __restrict__ s3)
{
    float* row = s3 + (size_t)blockIdx.x * SEQ;
    int t = threadIdx.x;
    __shared__ float red[256];
    float mx = -3.4e38f;
    for (int j = t; j < SEQ; j += 256) mx = fmaxf(mx, row[j]);
    red[t] = mx; __syncthreads();
    for (int o = 128; o > 0; o >>= 1) { if (t < o) red[t] = fmaxf(red[t], red[t+o]); __syncthreads(); }
    mx = red[0]; __syncthreads();
    float sum = 0.f;
    for (int j = t; j < SEQ; j += 256) { float e = expf(row[j] - mx); row[j] = e; sum += e; }
    red[t] = sum; __syncthreads();
    for (int o = 128; o > 0; o >>= 1) { if (t < o) red[t] += red[t+o]; __syncthreads(); }
    float inv = 1.0f / red[0];
    for (int j = t; j < SEQ; j += 256) row[j] *= inv;
}

__global__ __launch_bounds__(256)
void softmax256(float* __restrict__ P)
{
    int wid = threadIdx.x >> 6, lane = threadIdx.x & 63;
    float* p = P + ((size_t)blockIdx.x * 4 + wid) * MM + lane * 4;
    float4 v = *(float4*)p;
    float m = fmaxf(fmaxf(v.x, v.y), fmaxf(v.z, v.w));
    for (int o = 32; o > 0; o >>= 1) m = fmaxf(m, __shfl_xor(m, o));
    v.x = expf(v.x - m); v.y = expf(v.y - m);
    v.z = expf(v.z - m); v.w = expf(v.w - m);
    float s = v.x + v.y + v.z + v.w;
    for (int o = 32; o > 0; o >>= 1) s += __shfl_xor(s, o);
    float inv = 1.0f / s;
    v.x *= inv; v.y *= inv; v.z *= inv; v.w *= inv;
    *(float4*)p = v;
}

__global__ __launch_bounds__(512)
void res_add(const float* __restrict__ qkv, const float* __restrict__ rw,
             float* __restrict__ attn)
{
    int blk = blockIdx.x;
    int b = blk / (SEQ/16), i0 = (blk % (SEQ/16)) * 16;
    int c = threadIdx.x, h = c >> 6;
    __shared__ float w[NH*33];
    if (c < NH*33) w[c] = rw[c];
    __syncthreads();
    float acc[16];
    float* ab = attn + ((size_t)b * SEQ + i0) * D + c;
    #pragma unroll
    for (int rr = 0; rr < 16; rr++) acc[rr] = ab[(size_t)rr * D];
    const float* vb = qkv + (size_t)b * SEQ * 1536 + 2*D + c;
    const float* wh = w + h * 33;
    #pragma unroll 4
    for (int jj = 0; jj < 48; jj++) {
        int j = i0 + jj - 16;
        float val = ((unsigned)j < (unsigned)SEQ) ? vb[(size_t)j * 1536] : 0.f;
        #pragma unroll
        for (int rr = 0; rr < 16; rr++) {
            int ky = jj - rr;
            if (ky >= 0 && ky < 33) acc[rr] = fmaf(val, wh[ky], acc[rr]);
        }
    }
    #pragma unroll
    for (int rr = 0; rr < 16; rr++) ab[(size_t)rr * D] = acc[rr];
}

// ---------------------------------------------------------------- PPEG
__global__ __launch_bounds__(256)
void t_fw(const float* __restrict__ H, float* __restrict__ P)
{
    __shared__ float tile[32][33];
    int p0 = blockIdx.x * 32, c0 = blockIdx.y * 32, b = blockIdx.z;
    int tx = threadIdx.x & 31, ty = threadIdx.x >> 5;
    #pragma unroll
    for (int k = 0; k < 4; k++) {
        int pos = p0 + ty + k*8;
        tile[ty + k*8][tx] = (pos < 10000)
            ? H[((size_t)b * NTOK + 1 + pos) * D + c0 + tx] : 0.f;
    }
    __syncthreads();
    #pragma unroll
    for (int k = 0; k < 4; k++) {
        int c = c0 + ty + k*8, pos = p0 + tx;
        if (pos < 10000)
            P[((size_t)b * D + c) * 10000 + pos] = tile[tx][ty + k*8];
    }
}

__global__ __launch_bounds__(256)
void ppeg_conv(const float* __restrict__ P,
               const float* __restrict__ w7, const float* __restrict__ b7,
               const float* __restrict__ w5, const float* __restrict__ b5,
               const float* __restrict__ w3, const float* __restrict__ b3,
               float* __restrict__ Q)
{
    __shared__ float PS[106 * 107];
    __shared__ float w7s[49], w5s[25], w3s[9];
    int blk = blockIdx.x;
    int b = blk >> 9, c = blk & 511;
    int t = threadIdx.x;
    for (int idx = t; idx < 106*107; idx += 256) PS[idx] = 0.f;
    if (t < 49) w7s[t] = w7[(size_t)c * 49 + t];
    if (t < 25) w5s[t] = w5[(size_t)c * 25 + t];
    if (t < 9)  w3s[t] = w3[(size_t)c * 9 + t];
    float bsum = b7[c] + b5[c] + b3[c];
    __syncthreads();
    const float* Pin = P + ((size_t)b * D + c) * 10000;
    for (int p = t; p < 10000; p += 256) {
        int y = p / 100, x = p - y * 100;
        PS[(y + 3) * 107 + x + 3] = Pin[p];
    }
    __syncthreads();
    float* Qo = Q + ((size_t)b * D + c) * 10000;
    for (int p = t; p < 10000; p += 256) {
        int y = p / 100, x = p - y * 100;
        int base = (y + 3) * 107 + x + 3;
        float acc = PS[base] + bsum;
        #pragma unroll
        for (int ky = 0; ky < 7; ky++)
            #pragma unroll
            for (int kx = 0; kx < 7; kx++)
                acc = fmaf(PS[base + (ky-3)*107 + (kx-3)], w7s[ky*7+kx], acc);
        #pragma unroll
        for (int ky = 0; ky < 5; ky++)
            #pragma unroll
            for (int kx = 0; kx < 5; kx++)
                acc = fmaf(PS[base + (ky-2)*107 + (kx-2)], w5s[ky*5+kx], acc);
        #pragma unroll
        for (int ky = 0; ky < 3; ky++)
            #pragma unroll
            for (int kx = 0; kx < 3; kx++)
                acc = fmaf(PS[base + (ky-1)*107 + (kx-1)], w3s[ky*3+kx], acc);
        Qo[p] = acc;
    }
}

__global__ __launch_bounds__(256)
void t_bw(const float* __restrict__ Q, float* __restrict__ H)
{
    __shared__ float tile[32][33];
    int p0 = blockIdx.x * 32, c0 = blockIdx.y * 32, b = blockIdx.z;
    int tx = threadIdx.x & 31, ty = threadIdx.x >> 5;
    #pragma unroll
    for (int k = 0; k < 4; k++) {
        int c = c0 + ty + k*8, pos = p0 + tx;
        tile[ty + k*8][tx] = (pos < 10000)
            ? Q[((size_t)b * D + c) * 10000 + pos] : 0.f;
    }
    __syncthreads();
    #pragma unroll
    for (int k = 0; k < 4; k++) {
        int pos = p0 + ty + k*8;
        if (pos < 10000)
            H[((size_t)b * NTOK + 1 + pos) * D + c0 + tx] = tile[tx][ty + k*8];
    }
}

__global__ __launch_bounds__(512)
void final_head(const float* __restrict__ H, const float* __restrict__ g,
                const float* __restrict__ bt, const float* __restrict__ w2,
                const float* __restrict__ b2, float* __restrict__ out)
{
    int b = blockIdx.x, t = threadIdx.x;
    __shared__ float red[512];
    float v = H[(size_t)b * NTOK * D + t];
    red[t] = v; __syncthreads();
    for (int o = 256; o > 0; o >>= 1) { if (t < o) red[t] += red[t+o]; __syncthreads(); }
    float mu = red[0] * (1.0f / D); __syncthreads();
    float dv = v - mu;
    red[t] = dv*dv; __syncthreads();
    for (int o = 256; o > 0; o >>= 1) { if (t < o) red[t] += red[t+o]; __syncthreads(); }
    float rstd = rsqrtf(red[0] * (1.0f / D) + EPS_); __syncthreads();
    float xn = dv * rstd * g[t] + bt[t];
    red[t] = xn * w2[2*t]; __syncthreads();
    for (int o = 256; o > 0; o >>= 1) { if (t < o) red[t] += red[t+o]; __syncthreads(); }
    float l0 = red[0] + b2[0]; __syncthreads();
    red[t] = xn * w2[2*t+1]; __syncthreads();
    for (int o = 256; o > 0; o >>= 1) { if (t < o) red[t] += red[t+o]; __syncthreads(); }
    float l1 = red[0] + b2[1];
    if (t == 0) {
        out[b*2+0] = l0; out[b*2+1] = l1;
        float mx = fmaxf(l0, l1);
        float e0 = expf(l0 - mx), e1 = expf(l1 - mx);
        float ssum = e0 + e1;
        out[4 + b*2 + 0] = e0 / ssum;
        out[4 + b*2 + 1] = e1 / ssum;
        out[8 + b] = (l1 > l0) ? 1.0f : 0.0f;
    }
}

// ---------------------------------------------------------------------------
extern "C" void kernel_launch(void* const* d_in, const int* in_sizes, int n_in,
                              void* d_out, int out_size, void* d_ws, size_t ws_size,
                              hipStream_t stream)
{
    const float* x      = (const float*)d_in[0];
    const float* w_fc1  = (const float*)d_in[1];
    const float* b_fc1  = (const float*)d_in[2];
    const float* cls    = (const float*)d_in[3];
    const float* ln1_g  = (const float*)d_in[4];
    const float* ln1_b  = (const float*)d_in[5];
    const float* qkv1_w = (const float*)d_in[6];
    const float* out1_w = (const float*)d_in[7];
    const float* out1_b = (const float*)d_in[8];
    const float* res1_w = (const float*)d_in[9];
    const float* ln2_g  = (const float*)d_in[10];
    const float* ln2_b  = (const float*)d_in[11];
    const float* qkv2_w = (const float*)d_in[12];
    const float* out2_w = (const float*)d_in[13];
    const float* out2_b = (const float*)d_in[14];
    const float* res2_w = (const float*)d_in[15];
    const float* pw7 = (const float*)d_in[16];
    const float* pb7 = (const float*)d_in[17];
    const float* pw5 = (const float*)d_in[18];
    const float* pb5 = (const float*)d_in[19];
    const float* pw3 = (const float*)d_in[20];
    const float* pb3 = (const float*)d_in[21];
    const float* lnf_g = (const float*)d_in[22];
    const float* lnf_b = (const float*)d_in[23];
    const float* w_fc2 = (const float*)d_in[24];
    const float* b_fc2 = (const float*)d_in[25];

    // workspace carve-up — total 80,233,536 floats = 320.9 MB,
    // strictly below the R2-proven 321.98 MB footprint.
    float* ws = (float*)d_ws;
    size_t off = 0;
    auto alloc = [&](size_t n) { float* p = ws + off; off += (n + 63) & ~(size_t)63; return p; };
    float* H    = alloc((size_t)BB * NTOK * D);
    float* LN   = alloc((size_t)BB * SEQ * D);      // aliased: VT bf16 pair / ATTN
    float* QKV  = alloc((size_t)BB * SEQ * 3 * D);
    float* QL   = alloc((size_t)BB * NH * MM * DH);
    float* KLT  = alloc((size_t)BB * NH * DH * MM);
    float* A2   = alloc((size_t)BB * NH * MM * MM);
    float* ZA   = alloc((size_t)BB * NH * MM * MM);
    float* ZB   = alloc((size_t)BB * NH * MM * MM); // aliased: A3VT/WBT after pinv
    float* XZ   = alloc((size_t)BB * NH * MM * MM);
    float* A3V  = alloc((size_t)BB * NH * MM * DH);
    float* WB   = alloc((size_t)BB * NH * MM * DH);
    float* S3   = alloc((size_t)8 * MM * SEQ);      // scores / P / pinv-T bf16 / ppeg planes
    float* SCR  = alloc(64);
    auto ualloc = [&](size_t n) { ushort* p = (ushort*)(ws + off); off += ((n + 127) / 2) & ~(size_t)63; return p; };
    ushort* WTfcH = ualloc((size_t)512 * 1024);
    ushort* WTfcL = ualloc((size_t)512 * 1024);
    ushort* WTqH  = ualloc((size_t)1536 * 512);     // shared by both attn layers (lazy)
    ushort* WTqL  = ualloc((size_t)1536 * 512);
    ushort* WToH  = ualloc((size_t)512 * 512);
    ushort* WToL  = ualloc((size_t)512 * 512);
    ushort* klBH  = ualloc((size_t)16 * MM * DH);
    ushort* klBL  = ualloc((size_t)16 * MM * DH);
    // aliases
    float*  ATTN = LN;
    ushort* VTH  = (ushort*)LN;                       // [16][64][SEQ]
    ushort* VTL  = VTH + (size_t)16 * DH * SEQ;       // exactly fills LN
    ushort* A3VTH = (ushort*)ZB;                      // ZB dead after pinv (z ends in ZA)
    ushort* A3VTL = A3VTH + (size_t)16 * DH * MM;
    ushort* WBTH  = A3VTL + (size_t)16 * DH * MM;
    ushort* WBTL  = WBTH  + (size_t)16 * DH * MM;     // 4*262144 us = 524288 fl <= ZB
    ushort* PT   = (ushort*)S3;                       // pinv transposed bf16 chain
    const size_t PS = (size_t)16 * 65536;
    ushort* zTAH = PT;            ushort* zTAL = PT + PS;
    ushort* zTBH = PT + 2*PS;     ushort* zTBL = PT + 3*PS;
    ushort* XZTH = PT + 4*PS;     ushort* XZTL = PT + 5*PS;
    ushort* T1TH = PT + 6*PS;     ushort* T1TL = PT + 7*PS;
    ushort* T2TH = PT + 8*PS;     ushort* T2TL = PT + 9*PS;
    (void)ws_size; (void)in_sizes; (void)n_in; (void)out_size;

    // 0) fc1 weight prep + fc1
    convsplitT<<<dim3(32,16,1), 256, 0, stream>>>(w_fc1, WTfcH, WTfcL, 1024, 512, 512, 0,0,0, 1024, 0);
    for (int b = 0; b < BB; b++)
        mgemm128<<<dim3(4, 79), 256, 0, stream>>>(x + (size_t)b*N0*DIN, DIN,
            WTfcH, WTfcL, 1024, H + ((size_t)b*NTOK + 1)*D, D, b_fc1,
            N0, D, DIN, FLAG_BIAS|FLAG_RELU, 0, 1.f);
    fill_cls<<<BB, D, 0, stream>>>(cls, H);

    auto attention = [&](const float* lg, const float* lb,
                         const float* qw, const float* ow,
                         const float* ob, const float* rw)
    {
        // lazy weight conversion into the shared buffers
        convsplitT<<<dim3(16,48,1), 256, 0, stream>>>(qw, WTqH, WTqL, 512, 1536, 1536, 0,0,0, 512, 0);
        convsplitT<<<dim3(16,16,1), 256, 0, stream>>>(ow, WToH, WToL, 512, 512, 512, 0,0,0, 512, 0);
        ln_pad<<<BB*SEQ, 256, 0, stream>>>(H, lg, lb, LN);
        mgemm128<<<dim3(12, 160), 256, 0, stream>>>(LN, D, WTqH, WTqL, D,
            QKV, 3*D, nullptr, BB*SEQ, 3*D, D, 0, D, 0.125f);
        // V -> transposed split bf16 [slab][64][SEQ]  (overwrites LN)
        convsplitT<<<dim3(320, 2, 16), 256, 0, stream>>>(QKV + 2*D, VTH, VTL,
            SEQ, DH, 1536, (long long)SEQ*1536, 64, 0, SEQ, (long long)DH*SEQ);
        landmarks<<<BB*MM, 512, 0, stream>>>(QKV, QL, KLT, klBH, klBL);
        s2_softmax<<<BB*NH*MM, 256, 0, stream>>>(QL, KLT, A2);
        zero_scr<<<1, 64, 0, stream>>>(SCR);
        a2_alpha<<<BB*NH, 256, 0, stream>>>(A2, SCR);
        z_init<<<BB*NH*MM*MM/256, 256, 0, stream>>>(A2, SCR, ZA, zTAH, zTAL);
        float* z = ZA; float* zn = ZB;
        ushort *zTcH = zTAH, *zTcL = zTAL, *zTnH = zTBH, *zTnL = zTBL;
        for (int it = 0; it < 6; it++) {
            dim3 g(4, 4, 16);
            // XZ = A2 @ z
            mbgemm64<<<g,256,0,stream>>>(A2, 0,0,65536LL, MM,
                zTcH, zTcL, nullptr, 8LL*65536, 65536LL, MM,
                XZ, 0,0,65536LL, MM, XZTH, XZTL, 65536LL, MM,
                MM, MM, MM, 1, 0.f, 1.f, 1.f, 0, 0);
            // T1 = 7*XZ - XZ@XZ   (bf16-T emit only)
            mbgemm64<<<g,256,0,stream>>>(XZ, 0,0,65536LL, MM,
                XZTH, XZTL, nullptr, 8LL*65536, 65536LL, MM,
                nullptr, 0,0,0, MM, T1TH, T1TL, 65536LL, MM,
                MM, MM, MM, 1, 7.f, -1.f, 1.f, 0, 0);
            // T2 = 15*XZ - XZ@T1  (bf16-T emit only)
            mbgemm64<<<g,256,0,stream>>>(XZ, 0,0,65536LL, MM,
                T1TH, T1TL, nullptr, 8LL*65536, 65536LL, MM,
                nullptr, 0,0,0, MM, T2TH, T2TL, 65536LL, MM,
                MM, MM, MM, 1, 15.f, -1.f, 1.f, 0, 0);
            // zn = 0.25*(13*z - z@T2)
            mbgemm64<<<g,256,0,stream>>>(z, 0,0,65536LL, MM,
                T2TH, T2TL, nullptr, 8LL*65536, 65536LL, MM,
                zn, 0,0,65536LL, MM, zTnH, zTnL, 65536LL, MM,
                MM, MM, MM, 1, 13.f, -1.f, 0.25f, 0, 0);
            float* ts = z; z = zn; zn = ts;
            ushort* uh = zTcH; zTcH = zTnH; zTnH = uh;
            ushort* ul = zTcL; zTcL = zTnL; zTnL = ul;
        }
        // z is now ZA (6 swaps). ZB becomes free for A3VT/WBT.
        for (int grp = 0; grp < 2; grp++) {
            int slab0 = grp * 8;
            // S3 = q_l @ k^T
            mbgemm64<<<dim3(160, 4, 8), 256, 0, stream>>>(QL, 8LL*16384, 16384LL, 0, DH,
                nullptr, nullptr, QKV + D, (long long)SEQ*1536, 64LL, 1536,
                S3, 0,0,(long long)MM*SEQ, SEQ, nullptr, nullptr, 0, 0,
                MM, SEQ, DH, 1, 0.f, 1.f, 1.f, slab0, 0);
            s3_softmax<<<8*MM, 256, 0, stream>>>(S3);
            hipMemsetAsync(A3V + (size_t)slab0 * MM * DH, 0,
                           (size_t)8 * MM * DH * sizeof(float), stream);
            // A3V += S3 @ v  (split-K 16, atomic)
            mbgemm64<<<dim3(1, 4, 8*16), 256, 0, stream>>>(S3, 0,0,(long long)MM*SEQ, SEQ,
                VTH, VTL, nullptr, 8LL*DH*SEQ, (long long)DH*SEQ, SEQ,
                A3V, 8LL*16384, 16384LL, 0, DH, nullptr, nullptr, 0, 0,
                MM, DH, SEQ, 16, 0.f, 1.f, 1.f, slab0, FLAG_ATOMIC);
        }
        convsplitT<<<dim3(8, 2, 16), 256, 0, stream>>>(A3V, A3VTH, A3VTL,
            MM, DH, DH, 0, 0, 16384LL, MM, 16384LL);
        // WB = z @ A3V  (emit WBT)
        mbgemm64<<<dim3(1, 4, 16), 256, 0, stream>>>(z, 0,0,65536LL, MM,
            A3VTH, A3VTL, nullptr, 8LL*16384, 16384LL, MM,
            WB, 8LL*16384, 16384LL, 0, DH, WBTH, WBTL, 16384LL, MM,
            MM, DH, MM, 1, 0.f, 1.f, 1.f, 0, 0);
        // a1 pipeline: P = softmax(q@kl^T) ; ATTN = P @ WB
        for (int grp = 0; grp < 2; grp++) {
            int slab0 = grp * 8;
            mbgemm64<<<dim3(4, 160, 8), 256, 0, stream>>>(QKV, (long long)SEQ*1536, 64LL, 0, 1536,
                klBH, klBL, nullptr, 8LL*16384, 16384LL, DH,
                S3, 0,0,(long long)SEQ*MM, MM, nullptr, nullptr, 0, 0,
                SEQ, MM, DH, 1, 0.f, 1.f, 1.f, slab0, 0);
            softmax256<<<8*SEQ/4, 256, 0, stream>>>(S3);
            mbgemm64<<<dim3(1, 160, 8), 256, 0, stream>>>(S3, 0,0,(long long)SEQ*MM, MM,
                WBTH, WBTL, nullptr, 8LL*16384, 16384LL, MM,
                ATTN, (long long)SEQ*D, 64LL, 0, D, nullptr, nullptr, 0, 0,
                SEQ, DH, MM, 1, 0.f, 1.f, 1.f, slab0, 0);
        }
        res_add<<<BB*SEQ/16, 512, 0, stream>>>(QKV, rw, ATTN);
        for (int b = 0; b < BB; b++)
            mgemm128<<<dim3(4, 79), 256, 0, stream>>>(ATTN + ((size_t)b*SEQ + PADR)*D, D,
                WToH, WToL, D, H + (size_t)b*NTOK*D, D, ob,
                NTOK, D, D, FLAG_BIAS|FLAG_ACC, 0, 1.f);
    };

    attention(ln1_g, ln1_b, qkv1_w, out1_w, out1_b, res1_w);

    {   // PPEG (planes inside S3 region)
        float* Pp = S3;
        float* Qp = S3 + (size_t)BB * D * 10000;
        dim3 tg((10000 + 31)/32, D/32, BB);
        t_fw<<<tg, 256, 0, stream>>>(H, Pp);
        ppeg_conv<<<BB*D, 256, 0, stream>>>(Pp, pw7, pb7, pw5, pb5, pw3, pb3, Qp);
        t_bw<<<tg, 256, 0, stream>>>(Qp, H);
    }

    attention(ln2_g, ln2_b, qkv2_w, out2_w, out2_b, res2_w);

    final_head<<<BB, 512, 0, stream>>>(H, lnf_g, lnf_b, w_fc2, b_fc2, (float*)d_out);
}